// Round 2
// baseline (18778.784 us; speedup 1.0000x reference)
//
#include <hip/hip_runtime.h>
#include <hip/hip_bf16.h>
#include <math.h>

#define N_NODES 10000
#define N_EDGES 160000
#define IN_DIM  512
#define HID     1024

// ---------------------------------------------------------------------------
// CSR build: histogram by dst, prefix scan, scatter packed (dir<<16)|src
// ---------------------------------------------------------------------------
__global__ void k_hist(const int* __restrict__ ei, int* __restrict__ deg, int ne) {
    int e = blockIdx.x * blockDim.x + threadIdx.x;
    if (e < ne) atomicAdd(&deg[ei[2 * e + 1]], 1);
}

__global__ void k_scan(const int* __restrict__ deg, int* __restrict__ offs, int n) {
    __shared__ int s[1024];
    __shared__ int base_s;
    int t = threadIdx.x;
    if (t == 0) base_s = 0;
    __syncthreads();
    int nchunk = (n + 1023) / 1024;
    for (int ch = 0; ch < nchunk; ++ch) {
        int i = ch * 1024 + t;
        int v = (i < n) ? deg[i] : 0;
        s[t] = v;
        __syncthreads();
        for (int off = 1; off < 1024; off <<= 1) {
            int add = (t >= off) ? s[t - off] : 0;
            __syncthreads();
            s[t] += add;
            __syncthreads();
        }
        int incl = s[t];
        int base = base_s;
        if (i < n) offs[i] = base + incl - v;   // exclusive
        __syncthreads();
        if (t == 1023) base_s = base + s[1023];
        __syncthreads();
    }
    if (t == 0) offs[n] = base_s;
}

__global__ void k_copy_int(const int* __restrict__ a, int* __restrict__ b, int n) {
    int i = blockIdx.x * blockDim.x + threadIdx.x;
    if (i < n) b[i] = a[i];
}

__global__ void k_scatter(const int* __restrict__ ei, const int* __restrict__ ed,
                          int* __restrict__ cur, int* __restrict__ esort, int ne) {
    int e = blockIdx.x * blockDim.x + threadIdx.x;
    if (e < ne) {
        int dst = ei[2 * e + 1];
        int pos = atomicAdd(&cur[dst], 1);
        esort[pos] = (ed[e] << 16) | ei[2 * e];
    }
}

// bias precompute: bfb = b_f + b_b ; brz = (b_ih + b_hh)[0:2H]
__global__ void k_prep(const float* __restrict__ b_f, const float* __restrict__ b_b,
                       const float* __restrict__ b_ih, const float* __restrict__ b_hh,
                       float* __restrict__ bfb, float* __restrict__ brz) {
    int i = blockIdx.x * blockDim.x + threadIdx.x;
    if (i < HID) bfb[i] = b_f[i] + b_b[i];
    if (i < 2 * HID) brz[i] = b_ih[i] + b_hh[i];
}

// ---------------------------------------------------------------------------
// Aggregation: one block per node, 256 thr x 4 channels (float4).
// ---------------------------------------------------------------------------
__global__ __launch_bounds__(256) void k_agg(
    const float* __restrict__ h, const int* __restrict__ offs,
    const int* __restrict__ esort,
    float* __restrict__ aggF, float* __restrict__ aggB, float* __restrict__ aggU) {
    int node = blockIdx.x;
    int c = threadIdx.x * 4;
    float4 f = make_float4(0.f, 0.f, 0.f, 0.f);
    float4 b = f, u = f;
    int beg = offs[node], end = offs[node + 1];
    for (int e = beg; e < end; ++e) {
        int pk = esort[e];
        int src = pk & 0xFFFF;
        int dir = pk >> 16;
        float4 v = *(const float4*)(h + (size_t)src * HID + c);
        if (dir == 0)      { f.x += v.x; f.y += v.y; f.z += v.z; f.w += v.w; }
        else if (dir == 1) { b.x += v.x; b.y += v.y; b.z += v.z; b.w += v.w; }
        else               { u.x += v.x; u.y += v.y; u.z += v.z; u.w += v.w; }
    }
    size_t o = (size_t)node * HID + c;
    *(float4*)(aggF + o) = f;
    *(float4*)(aggB + o) = b;
    *(float4*)(aggU + o) = u;
}

// ---------------------------------------------------------------------------
// fp32 GEMM: acc = A1@W1 [+ A2@W2], W column-sliced via ldw.
// epi 0: C = acc + bias [+ U]
// epi 1: C = sigmoid(acc + bias)
// epi 2: C = relu((1-Z)*tanh(acc+bias + R*HG) + Z*C)   (C read-then-write in place)
// 128x128 tile, K-step 16, 256 threads, 8x8 microtile.
// ---------------------------------------------------------------------------
#define TM 128
#define TN 128
#define TK 16

__device__ inline float sig_(float x)  { return 1.0f / (1.0f + __expf(-x)); }
__device__ inline float tanh_(float x) { return 2.0f / (1.0f + __expf(-2.0f * x)) - 1.0f; }

__global__ __launch_bounds__(256) void gemm_fp32(
    const float* __restrict__ A1, const float* __restrict__ W1,
    const float* __restrict__ A2, const float* __restrict__ W2,
    const float* __restrict__ U, const float* __restrict__ bias,
    const float* __restrict__ R, const float* __restrict__ Z,
    const float* __restrict__ HG,
    float* __restrict__ C, int M, int N, int K, int ldw, int epi) {
    __shared__ float As[TK][TM + 4];
    __shared__ float Bs[TK][TN + 4];
    int m0 = blockIdx.x * TM, n0 = blockIdx.y * TN;
    int t = threadIdx.x;
    int tx = t & 15, ty = t >> 4;

    float acc[8][8];
#pragma unroll
    for (int i = 0; i < 8; i++)
#pragma unroll
        for (int j = 0; j < 8; j++) acc[i][j] = 0.f;

    int npairs = (A2 != nullptr) ? 2 : 1;
    for (int p = 0; p < npairs; ++p) {
        const float* A = p ? A2 : A1;
        const float* W = p ? W2 : W1;
        for (int k0 = 0; k0 < K; k0 += TK) {
            {   // A tile: 128 rows x 16 k; transpose into As[k][m]
                int row = t >> 1;
                int col = (t & 1) * 8;
                int m = m0 + row;
                float4 v0 = make_float4(0.f, 0.f, 0.f, 0.f), v1 = v0;
                if (m < M) {
                    const float* ap = A + (size_t)m * K + k0 + col;
                    v0 = *(const float4*)(ap);
                    v1 = *(const float4*)(ap + 4);
                }
                As[col + 0][row] = v0.x; As[col + 1][row] = v0.y;
                As[col + 2][row] = v0.z; As[col + 3][row] = v0.w;
                As[col + 4][row] = v1.x; As[col + 5][row] = v1.y;
                As[col + 6][row] = v1.z; As[col + 7][row] = v1.w;
            }
            {   // W tile: 16 k-rows x 128 n (row stride ldw)
                int row = t >> 4;
                int col = (t & 15) * 8;
                const float* wp = W + (size_t)(k0 + row) * ldw + n0 + col;
                float4 v0 = *(const float4*)(wp);
                float4 v1 = *(const float4*)(wp + 4);
                *(float4*)&Bs[row][col]     = v0;
                *(float4*)&Bs[row][col + 4] = v1;
            }
            __syncthreads();
#pragma unroll
            for (int k = 0; k < TK; ++k) {
                float a[8], bb[8];
                float4 a0 = *(const float4*)&As[k][ty * 4];
                float4 a1 = *(const float4*)&As[k][64 + ty * 4];
                float4 b0 = *(const float4*)&Bs[k][tx * 4];
                float4 b1 = *(const float4*)&Bs[k][64 + tx * 4];
                a[0]=a0.x; a[1]=a0.y; a[2]=a0.z; a[3]=a0.w;
                a[4]=a1.x; a[5]=a1.y; a[6]=a1.z; a[7]=a1.w;
                bb[0]=b0.x; bb[1]=b0.y; bb[2]=b0.z; bb[3]=b0.w;
                bb[4]=b1.x; bb[5]=b1.y; bb[6]=b1.z; bb[7]=b1.w;
#pragma unroll
                for (int i = 0; i < 8; i++)
#pragma unroll
                    for (int j = 0; j < 8; j++) acc[i][j] += a[i] * bb[j];
            }
            __syncthreads();
        }
    }
    // epilogue
#pragma unroll
    for (int i = 0; i < 8; i++) {
        int m = m0 + ((i < 4) ? (ty * 4 + i) : (64 + ty * 4 + (i - 4)));
        if (m >= M) continue;
#pragma unroll
        for (int jj = 0; jj < 2; jj++) {
            int nb = n0 + ((jj == 0) ? (tx * 4) : (64 + tx * 4));
            float v[4] = { acc[i][jj*4+0], acc[i][jj*4+1], acc[i][jj*4+2], acc[i][jj*4+3] };
            float4 bv = *(const float4*)(bias + nb);
            v[0] += bv.x; v[1] += bv.y; v[2] += bv.z; v[3] += bv.w;
            size_t co = (size_t)m * N + nb;
            float4 r;
            if (epi == 0) {
                if (U) {
                    float4 uv = *(const float4*)(U + co);
                    v[0] += uv.x; v[1] += uv.y; v[2] += uv.z; v[3] += uv.w;
                }
                r.x = v[0]; r.y = v[1]; r.z = v[2]; r.w = v[3];
            } else if (epi == 1) {
                r.x = sig_(v[0]); r.y = sig_(v[1]); r.z = sig_(v[2]); r.w = sig_(v[3]);
            } else {
                float4 rr = *(const float4*)(R + co);
                float4 zz = *(const float4*)(Z + co);
                float4 hg = *(const float4*)(HG + co);
                float4 ho = *(const float4*)(C + co);
                float nn;
                nn  = tanh_(v[0] + rr.x * hg.x);
                r.x = fmaxf((1.f - zz.x) * nn + zz.x * ho.x, 0.f);
                nn  = tanh_(v[1] + rr.y * hg.y);
                r.y = fmaxf((1.f - zz.y) * nn + zz.y * ho.y, 0.f);
                nn  = tanh_(v[2] + rr.z * hg.z);
                r.z = fmaxf((1.f - zz.z) * nn + zz.z * ho.z, 0.f);
                nn  = tanh_(v[3] + rr.w * hg.w);
                r.w = fmaxf((1.f - zz.w) * nn + zz.w * ho.w, 0.f);
            }
            *(float4*)(C + co) = r;
        }
    }
}

// ---------------------------------------------------------------------------
// Readout
// ---------------------------------------------------------------------------
__global__ void k_colmax(const float* __restrict__ h, float* __restrict__ hmax) {
    int c = blockIdx.x * blockDim.x + threadIdx.x;     // column
    int r0 = blockIdx.y * (N_NODES / 10);              // 10 row chunks of 1000
    float m = 0.f;                                      // h >= 0 (post-relu)
    for (int r = r0; r < r0 + N_NODES / 10; ++r)
        m = fmaxf(m, h[(size_t)r * HID + c]);
    atomicMax((int*)&hmax[c], __float_as_int(m));       // valid for floats >= 0
}

__global__ void k_r1(const float* __restrict__ hmax, const float* __restrict__ W,
                     const float* __restrict__ b, float* __restrict__ t1) {
    int j = blockIdx.x * blockDim.x + threadIdx.x;
    if (j >= HID) return;
    float acc = b[j];
    for (int k = 0; k < HID; ++k) acc += hmax[k] * W[(size_t)k * HID + j];
    t1[j] = fmaxf(acc, 0.f);
}

__global__ void k_r2(const float* __restrict__ t1, const float* __restrict__ W2,
                     const float* __restrict__ b2, float* __restrict__ out) {
    __shared__ float s[256];
    int t = threadIdx.x;
    float acc = 0.f;
    for (int i = t; i < HID; i += 256) acc += t1[i] * W2[i];
    s[t] = acc;
    __syncthreads();
    for (int st = 128; st > 0; st >>= 1) {
        if (t < st) s[t] += s[t + st];
        __syncthreads();
    }
    if (t == 0) out[0] = s[0] + b2[0];
}

// ---------------------------------------------------------------------------
extern "C" void kernel_launch(void* const* d_in, const int* in_sizes, int n_in,
                              void* d_out, int out_size, void* d_ws, size_t ws_size,
                              hipStream_t stream) {
    const float* node_features = (const float*)d_in[0];
    const int*   edge_index    = (const int*)d_in[1];
    const int*   edge_dirs     = (const int*)d_in[2];
    const float* W_in = (const float*)d_in[3];
    const float* b_in = (const float*)d_in[4];
    const float* W_f  = (const float*)d_in[5];
    const float* b_f  = (const float*)d_in[6];
    const float* W_b  = (const float*)d_in[7];
    const float* b_b  = (const float*)d_in[8];
    const float* W_ih = (const float*)d_in[9];
    const float* b_ih = (const float*)d_in[10];
    const float* W_hh = (const float*)d_in[11];
    const float* b_hh = (const float*)d_in[12];
    const float* W_r1 = (const float*)d_in[13];
    const float* b_r1 = (const float*)d_in[14];
    const float* W_r2 = (const float*)d_in[15];
    const float* b_r2 = (const float*)d_in[16];
    float* out = (float*)d_out;

    // workspace layout -- compact: 5*NH floats (~205 MB) + ~0.8 MB ints
    float* ws = (float*)d_ws;
    size_t off = 0;
    auto alloc = [&](size_t n) { float* p = ws + off; off += n; return p; };
    const size_t NH = (size_t)N_NODES * HID;
    float* hc   = alloc(NH);   // h, updated in place by GRU-epilogue GEMM
    float* msg  = alloc(NH);
    float* bufA = alloc(NH);   // aggF -> r
    float* bufB = alloc(NH);   // aggB -> z
    float* bufC = alloc(NH);   // aggU -> hn-gate
    float* bfb  = alloc(HID);
    float* brz  = alloc(2 * HID);
    float* hmax = alloc(HID);
    float* t1   = alloc(HID);
    int* ibase  = (int*)(ws + off);
    int* deg    = ibase;                // N_NODES
    int* offs   = ibase + N_NODES;      // N_NODES+1
    int* cur    = offs + N_NODES + 1;   // N_NODES
    int* esort  = cur + N_NODES;        // N_EDGES

    // ---- CSR build + bias prep ----
    hipMemsetAsync(deg, 0, N_NODES * sizeof(int), stream);
    hipMemsetAsync(hmax, 0, HID * sizeof(float), stream);
    k_hist<<<(N_EDGES + 255) / 256, 256, 0, stream>>>(edge_index, deg, N_EDGES);
    k_scan<<<1, 1024, 0, stream>>>(deg, offs, N_NODES);
    k_copy_int<<<(N_NODES + 255) / 256, 256, 0, stream>>>(offs, cur, N_NODES);
    k_scatter<<<(N_EDGES + 255) / 256, 256, 0, stream>>>(edge_index, edge_dirs, cur,
                                                         esort, N_EDGES);
    k_prep<<<8, 256, 0, stream>>>(b_f, b_b, b_ih, b_hh, bfb, brz);

    dim3 g1((N_NODES + TM - 1) / TM, HID / TN);  // 79 x 8

    // ---- input projection: hc = X @ W_in + b_in ----
    gemm_fp32<<<g1, 256, 0, stream>>>(node_features, W_in, nullptr, nullptr,
                                      nullptr, b_in, nullptr, nullptr, nullptr,
                                      hc, N_NODES, HID, IN_DIM, HID, 0);

    for (int layer = 0; layer < 8; ++layer) {
        k_agg<<<N_NODES, 256, 0, stream>>>(hc, offs, esort, bufA, bufB, bufC);
        // msg = aggF@W_f + aggB@W_b + aggU + (b_f+b_b)
        gemm_fp32<<<g1, 256, 0, stream>>>(bufA, W_f, bufB, W_b, bufC, bfb,
                                          nullptr, nullptr, nullptr,
                                          msg, N_NODES, HID, HID, HID, 0);
        // r = sigmoid(msg@Wih[:,0:H] + hc@Whh[:,0:H] + brz[0:H])  -> bufA
        gemm_fp32<<<g1, 256, 0, stream>>>(msg, W_ih, hc, W_hh, nullptr, brz,
                                          nullptr, nullptr, nullptr,
                                          bufA, N_NODES, HID, HID, 3 * HID, 1);
        // z = sigmoid(msg@Wih[:,H:2H] + hc@Whh[:,H:2H] + brz[H:2H]) -> bufB
        gemm_fp32<<<g1, 256, 0, stream>>>(msg, W_ih + HID, hc, W_hh + HID, nullptr,
                                          brz + HID, nullptr, nullptr, nullptr,
                                          bufB, N_NODES, HID, HID, 3 * HID, 1);
        // hn-gate = hc@Whh[:,2H:3H] + b_hh[2H:3H] -> bufC
        gemm_fp32<<<g1, 256, 0, stream>>>(hc, W_hh + 2 * HID, nullptr, nullptr,
                                          nullptr, b_hh + 2 * HID,
                                          nullptr, nullptr, nullptr,
                                          bufC, N_NODES, HID, HID, 3 * HID, 0);
        // hc = relu((1-z)*tanh(msg@Wih[:,2H:]+b_ih[2H:] + r*hn_gate) + z*hc)
        gemm_fp32<<<g1, 256, 0, stream>>>(msg, W_ih + 2 * HID, nullptr, nullptr,
                                          nullptr, b_ih + 2 * HID,
                                          bufA, bufB, bufC,
                                          hc, N_NODES, HID, HID, 3 * HID, 2);
    }

    // ---- readout ----
    {
        dim3 gm(HID / 256, 10);
        k_colmax<<<gm, 256, 0, stream>>>(hc, hmax);
    }
    k_r1<<<HID / 256, 256, 0, stream>>>(hmax, W_r1, b_r1, t1);
    k_r2<<<1, 256, 0, stream>>>(t1, W_r2, b_r2, out);
}

// Round 3
// 3760.357 us; speedup vs baseline: 4.9939x; 4.9939x over previous
//
#include <hip/hip_runtime.h>
#include <hip/hip_bf16.h>
#include <math.h>

#define N_NODES 10000
#define N_EDGES 160000
#define IN_DIM  512
#define HID     1024
#define M_PAD   10112   // 79 * 128

typedef _Float16 half8 __attribute__((ext_vector_type(8)));
typedef float    floatx4 __attribute__((ext_vector_type(4)));

__device__ inline void gld16(const void* g, void* l) {
    __builtin_amdgcn_global_load_lds(
        (const __attribute__((address_space(1))) unsigned int*)g,
        (__attribute__((address_space(3))) unsigned int*)l, 16, 0, 0);
}

__device__ inline float sig_(float x)  { return 1.0f / (1.0f + __expf(-x)); }
__device__ inline float tanh_(float x) { return 2.0f / (1.0f + __expf(-2.0f * x)) - 1.0f; }

// ---------------------------------------------------------------------------
// CSR build: histogram by dst, prefix scan, scatter packed (dir<<16)|src
// ---------------------------------------------------------------------------
__global__ void k_hist(const int* __restrict__ ei, int* __restrict__ deg, int ne) {
    int e = blockIdx.x * blockDim.x + threadIdx.x;
    if (e < ne) atomicAdd(&deg[ei[2 * e + 1]], 1);
}

__global__ void k_scan(const int* __restrict__ deg, int* __restrict__ offs, int n) {
    __shared__ int s[1024];
    __shared__ int base_s;
    int t = threadIdx.x;
    if (t == 0) base_s = 0;
    __syncthreads();
    int nchunk = (n + 1023) / 1024;
    for (int ch = 0; ch < nchunk; ++ch) {
        int i = ch * 1024 + t;
        int v = (i < n) ? deg[i] : 0;
        s[t] = v;
        __syncthreads();
        for (int off = 1; off < 1024; off <<= 1) {
            int add = (t >= off) ? s[t - off] : 0;
            __syncthreads();
            s[t] += add;
            __syncthreads();
        }
        int incl = s[t];
        int base = base_s;
        if (i < n) offs[i] = base + incl - v;   // exclusive
        __syncthreads();
        if (t == 1023) base_s = base + s[1023];
        __syncthreads();
    }
    if (t == 0) offs[n] = base_s;
}

__global__ void k_copy_int(const int* __restrict__ a, int* __restrict__ b, int n) {
    int i = blockIdx.x * blockDim.x + threadIdx.x;
    if (i < n) b[i] = a[i];
}

__global__ void k_scatter(const int* __restrict__ ei, const int* __restrict__ ed,
                          int* __restrict__ cur, int* __restrict__ esort, int ne) {
    int e = blockIdx.x * blockDim.x + threadIdx.x;
    if (e < ne) {
        int dst = ei[2 * e + 1];
        int pos = atomicAdd(&cur[dst], 1);
        esort[pos] = (ed[e] << 16) | ei[2 * e];
    }
}

// bias precompute: bfb = b_f + b_b ; brz = (b_ih + b_hh)[0:2H]
__global__ void k_prep(const float* __restrict__ b_f, const float* __restrict__ b_b,
                       const float* __restrict__ b_ih, const float* __restrict__ b_hh,
                       float* __restrict__ bfb, float* __restrict__ brz) {
    int i = blockIdx.x * blockDim.x + threadIdx.x;
    if (i < HID) bfb[i] = b_f[i] + b_b[i];
    if (i < 2 * HID) brz[i] = b_ih[i] + b_hh[i];
}

// fp32 KxN -> fp16 NxK transpose (weights)
__global__ __launch_bounds__(256) void k_transpose(const float* __restrict__ in,
                                                   _Float16* __restrict__ out,
                                                   int K, int N) {
    __shared__ float tile[32][33];
    int n0 = blockIdx.x * 32, k0 = blockIdx.y * 32;
    int tx = threadIdx.x & 31, ty = threadIdx.x >> 5;   // 32 x 8
#pragma unroll
    for (int r = 0; r < 4; ++r) {
        int k = k0 + ty + r * 8;
        tile[ty + r * 8][tx] = in[(size_t)k * N + n0 + tx];
    }
    __syncthreads();
#pragma unroll
    for (int r = 0; r < 4; ++r) {
        int n = n0 + ty + r * 8;
        out[(size_t)n * K + k0 + tx] = (_Float16)tile[tx][ty + r * 8];
    }
}

__global__ void k_cvt(const float* __restrict__ in, _Float16* __restrict__ out, int n) {
    int i = blockIdx.x * blockDim.x + threadIdx.x;
    if (i < n) out[i] = (_Float16)in[i];
}

// ---------------------------------------------------------------------------
// Aggregation: one block (128 thr) per node, 8 fp16 channels each (16B loads).
// ---------------------------------------------------------------------------
__global__ __launch_bounds__(128) void k_agg(
    const _Float16* __restrict__ h, const int* __restrict__ offs,
    const int* __restrict__ esort,
    _Float16* __restrict__ aggF, _Float16* __restrict__ aggB,
    _Float16* __restrict__ aggU) {
    int node = blockIdx.x;
    int c = threadIdx.x * 8;
    float f[8], b[8], u[8];
#pragma unroll
    for (int j = 0; j < 8; ++j) { f[j] = 0.f; b[j] = 0.f; u[j] = 0.f; }
    int beg = offs[node], end = offs[node + 1];
    for (int e = beg; e < end; ++e) {
        int pk = esort[e];
        int src = pk & 0xFFFF;
        int dir = pk >> 16;
        half8 v = *(const half8*)(h + (size_t)src * HID + c);
        if (dir == 0) {
#pragma unroll
            for (int j = 0; j < 8; ++j) f[j] += (float)v[j];
        } else if (dir == 1) {
#pragma unroll
            for (int j = 0; j < 8; ++j) b[j] += (float)v[j];
        } else {
#pragma unroll
            for (int j = 0; j < 8; ++j) u[j] += (float)v[j];
        }
    }
    size_t o = (size_t)node * HID + c;
    half8 vf, vb, vu;
#pragma unroll
    for (int j = 0; j < 8; ++j) {
        vf[j] = (_Float16)f[j]; vb[j] = (_Float16)b[j]; vu[j] = (_Float16)u[j];
    }
    *(half8*)(aggF + o) = vf;
    *(half8*)(aggB + o) = vb;
    *(half8*)(aggU + o) = vu;
}

// ---------------------------------------------------------------------------
// fp16 MFMA GEMM: acc(f32) = A1@B1t^T [+ A2@B2t^T]
//   A row-major M_PAD x K fp16, Bt row-major N x K fp16 (W transposed), N=1024.
// epi 0: v = acc+bias [+U];  write Cbf (fp16) [, Cf (fp32)]
// epi 1: v = sigmoid(acc+bias); write Cbf
// epi 2: GRU: nn=tanh(acc+bias+R*HG); o=relu((1-Z)*nn+Z*Hf); Hf=o, Cbf=o
// 128x128 tile, BK=32, 256 thr = 4 waves of 4x4 mfma_f32_16x16x32_f16.
// ---------------------------------------------------------------------------
#define BM 128
#define BN 128
#define BK 32

__global__ __launch_bounds__(256) void gemm_f16(
    const _Float16* __restrict__ A1, const _Float16* __restrict__ B1t,
    const _Float16* __restrict__ A2, const _Float16* __restrict__ B2t,
    const _Float16* __restrict__ U, const float* __restrict__ bias,
    const _Float16* __restrict__ R, const _Float16* __restrict__ Zg,
    const _Float16* __restrict__ HG, float* __restrict__ Hf,
    _Float16* __restrict__ Cbf, float* __restrict__ Cf,
    int M, int K, int epi) {
    __shared__ _Float16 As[BM * BK];
    __shared__ _Float16 Bs[BN * BK];
    int t = threadIdx.x;
    int m0 = blockIdx.x * BM, n0 = blockIdx.y * BN;
    int wid = t >> 6, lane = t & 63;
    int wm = wid >> 1, wn = wid & 1;
    int quad = lane >> 4, mr = lane & 15;

    floatx4 acc[4][4] = {};

    int npair = (A2 != nullptr) ? 2 : 1;
    for (int p = 0; p < npair; ++p) {
        const _Float16* A = p ? A2 : A1;
        const _Float16* B = p ? B2t : B1t;
        for (int k0 = 0; k0 < K; k0 += BK) {
            // stage A,B tiles: 8 KB each via global_load_lds width=16
#pragma unroll
            for (int i = 0; i < 2; ++i) {
                int row = i * 64 + (t >> 2);
                int ce = (t & 3) * 8;                    // fp16 element col
                gld16(A + (size_t)(m0 + row) * K + k0 + ce, As + i * 2048 + t * 8);
                gld16(B + (size_t)(n0 + row) * K + k0 + ce, Bs + i * 2048 + t * 8);
            }
            __syncthreads();
            half8 af[4], bfr[4];
#pragma unroll
            for (int i = 0; i < 4; ++i)
                af[i] = *(const half8*)(As + (wm * 64 + i * 16 + mr) * 32 + quad * 8);
#pragma unroll
            for (int j = 0; j < 4; ++j)
                bfr[j] = *(const half8*)(Bs + (wn * 64 + j * 16 + mr) * 32 + quad * 8);
#pragma unroll
            for (int i = 0; i < 4; ++i)
#pragma unroll
                for (int j = 0; j < 4; ++j)
                    acc[i][j] = __builtin_amdgcn_mfma_f32_16x16x32_f16(
                        af[i], bfr[j], acc[i][j], 0, 0, 0);
            __syncthreads();
        }
    }

    // epilogue: C layout col=lane&15, row=quad*4+reg
#pragma unroll
    for (int i = 0; i < 4; ++i) {
#pragma unroll
        for (int j = 0; j < 4; ++j) {
            int n = n0 + wn * 64 + j * 16 + mr;
            float bv = bias[n];
#pragma unroll
            for (int r = 0; r < 4; ++r) {
                int m = m0 + wm * 64 + i * 16 + quad * 4 + r;
                if (m >= M) continue;
                size_t idx = (size_t)m * HID + n;
                float v = acc[i][j][r] + bv;
                if (epi == 0) {
                    if (U) v += (float)U[idx];
                    if (Cf) Cf[idx] = v;
                    Cbf[idx] = (_Float16)v;
                } else if (epi == 1) {
                    Cbf[idx] = (_Float16)sig_(v);
                } else {
                    float rr = (float)R[idx], zz = (float)Zg[idx], hg = (float)HG[idx];
                    float hv = Hf[idx];
                    float nn = tanh_(v + rr * hg);
                    float o = fmaxf((1.f - zz) * nn + zz * hv, 0.f);
                    Hf[idx] = o;
                    Cbf[idx] = (_Float16)o;
                }
            }
        }
    }
}

// ---------------------------------------------------------------------------
// Readout (fp32)
// ---------------------------------------------------------------------------
__global__ void k_colmax(const float* __restrict__ h, float* __restrict__ hmax) {
    int c = blockIdx.x * blockDim.x + threadIdx.x;
    int r0 = blockIdx.y * (N_NODES / 10);
    float m = 0.f;                                      // h >= 0 post-relu
    for (int r = r0; r < r0 + N_NODES / 10; ++r)
        m = fmaxf(m, h[(size_t)r * HID + c]);
    atomicMax((int*)&hmax[c], __float_as_int(m));
}

__global__ void k_r1(const float* __restrict__ hmax, const float* __restrict__ W,
                     const float* __restrict__ b, float* __restrict__ t1) {
    int j = blockIdx.x * blockDim.x + threadIdx.x;
    if (j >= HID) return;
    float acc = b[j];
    for (int k = 0; k < HID; ++k) acc += hmax[k] * W[(size_t)k * HID + j];
    t1[j] = fmaxf(acc, 0.f);
}

__global__ void k_r2(const float* __restrict__ t1, const float* __restrict__ W2,
                     const float* __restrict__ b2, float* __restrict__ out) {
    __shared__ float s[256];
    int t = threadIdx.x;
    float acc = 0.f;
    for (int i = t; i < HID; i += 256) acc += t1[i] * W2[i];
    s[t] = acc;
    __syncthreads();
    for (int st = 128; st > 0; st >>= 1) {
        if (t < st) s[t] += s[t + st];
        __syncthreads();
    }
    if (t == 0) out[0] = s[0] + b2[0];
}

// ---------------------------------------------------------------------------
extern "C" void kernel_launch(void* const* d_in, const int* in_sizes, int n_in,
                              void* d_out, int out_size, void* d_ws, size_t ws_size,
                              hipStream_t stream) {
    const float* node_features = (const float*)d_in[0];
    const int*   edge_index    = (const int*)d_in[1];
    const int*   edge_dirs     = (const int*)d_in[2];
    const float* W_in = (const float*)d_in[3];
    const float* b_in = (const float*)d_in[4];
    const float* W_f  = (const float*)d_in[5];
    const float* b_f  = (const float*)d_in[6];
    const float* W_b  = (const float*)d_in[7];
    const float* b_b  = (const float*)d_in[8];
    const float* W_ih = (const float*)d_in[9];
    const float* b_ih = (const float*)d_in[10];
    const float* W_hh = (const float*)d_in[11];
    const float* b_hh = (const float*)d_in[12];
    const float* W_r1 = (const float*)d_in[13];
    const float* b_r1 = (const float*)d_in[14];
    const float* W_r2 = (const float*)d_in[15];
    const float* b_r2 = (const float*)d_in[16];
    float* out = (float*)d_out;

    // ---- workspace layout ----
    float* ws = (float*)d_ws;
    size_t off = 0;
    auto allocf = [&](size_t n) { float* p = ws + off; off += n; return p; };
    const size_t PH = (size_t)M_PAD * HID;
    float* h_f32 = allocf(PH);          // fp32 GRU state (rows < N_NODES used)
    float* bfb   = allocf(HID);
    float* brz   = allocf(2 * HID);
    float* hmax  = allocf(HID);
    float* t1    = allocf(HID);
    _Float16* hp = (_Float16*)(ws + off);
    size_t hoff = 0;
    auto alloch = [&](size_t n) { _Float16* p = hp + hoff; hoff += n; return p; };
    _Float16* h_bf  = alloch(PH);       // fp16 shadow of h
    _Float16* msg   = alloch(PH);
    _Float16* bufA  = alloch(PH);       // aggF -> r
    _Float16* bufB  = alloch(PH);       // aggB -> z
    _Float16* bufC  = alloch(PH);       // aggU -> hn-gate
    _Float16* X_bf  = alloch((size_t)M_PAD * IN_DIM);
    _Float16* Wint  = alloch((size_t)HID * IN_DIM);      // W_in^T  (1024 x 512)
    _Float16* Wft   = alloch((size_t)HID * HID);
    _Float16* Wbt   = alloch((size_t)HID * HID);
    _Float16* Wiht  = alloch((size_t)3 * HID * HID);     // 3072 x 1024
    _Float16* Whht  = alloch((size_t)3 * HID * HID);
    int* ibase = (int*)(hp + hoff);
    int* deg   = ibase;
    int* offs  = ibase + N_NODES;
    int* cur   = offs + N_NODES + 1;
    int* esort = cur + N_NODES;

    // ---- CSR build + prep ----
    hipMemsetAsync(deg, 0, N_NODES * sizeof(int), stream);
    hipMemsetAsync(hmax, 0, HID * sizeof(float), stream);
    k_hist<<<(N_EDGES + 255) / 256, 256, 0, stream>>>(edge_index, deg, N_EDGES);
    k_scan<<<1, 1024, 0, stream>>>(deg, offs, N_NODES);
    k_copy_int<<<(N_NODES + 255) / 256, 256, 0, stream>>>(offs, cur, N_NODES);
    k_scatter<<<(N_EDGES + 255) / 256, 256, 0, stream>>>(edge_index, edge_dirs, cur,
                                                         esort, N_EDGES);
    k_prep<<<8, 256, 0, stream>>>(b_f, b_b, b_ih, b_hh, bfb, brz);

    // weight transposes (fp32 KxN -> fp16 NxK)
    k_transpose<<<dim3(HID / 32, IN_DIM / 32), 256, 0, stream>>>(W_in, Wint, IN_DIM, HID);
    k_transpose<<<dim3(HID / 32, HID / 32), 256, 0, stream>>>(W_f, Wft, HID, HID);
    k_transpose<<<dim3(HID / 32, HID / 32), 256, 0, stream>>>(W_b, Wbt, HID, HID);
    k_transpose<<<dim3(3 * HID / 32, HID / 32), 256, 0, stream>>>(W_ih, Wiht, HID, 3 * HID);
    k_transpose<<<dim3(3 * HID / 32, HID / 32), 256, 0, stream>>>(W_hh, Whht, HID, 3 * HID);
    k_cvt<<<(N_NODES * IN_DIM + 255) / 256, 256, 0, stream>>>(node_features, X_bf,
                                                              N_NODES * IN_DIM);

    dim3 gg(M_PAD / BM, HID / BN);   // 79 x 8

    // ---- input projection: h = X @ W_in + b_in  (fp32 master + fp16 shadow) ----
    gemm_f16<<<gg, 256, 0, stream>>>(X_bf, Wint, nullptr, nullptr,
                                     nullptr, b_in, nullptr, nullptr, nullptr,
                                     nullptr, h_bf, h_f32, N_NODES, IN_DIM, 0);

    const size_t HH = (size_t)HID * HID;
    for (int layer = 0; layer < 8; ++layer) {
        k_agg<<<N_NODES, 128, 0, stream>>>(h_bf, offs, esort, bufA, bufB, bufC);
        // msg = aggF@W_f + aggB@W_b + aggU + (b_f+b_b)
        gemm_f16<<<gg, 256, 0, stream>>>(bufA, Wft, bufB, Wbt, bufC, bfb,
                                         nullptr, nullptr, nullptr, nullptr,
                                         msg, nullptr, N_NODES, HID, 0);
        // r = sigmoid(msg@Wih_r + h@Whh_r + brz_r) -> bufA
        gemm_f16<<<gg, 256, 0, stream>>>(msg, Wiht, h_bf, Whht, nullptr, brz,
                                         nullptr, nullptr, nullptr, nullptr,
                                         bufA, nullptr, N_NODES, HID, 1);
        // z = sigmoid(msg@Wih_z + h@Whh_z + brz_z) -> bufB
        gemm_f16<<<gg, 256, 0, stream>>>(msg, Wiht + HH, h_bf, Whht + HH, nullptr,
                                         brz + HID, nullptr, nullptr, nullptr, nullptr,
                                         bufB, nullptr, N_NODES, HID, 1);
        // hn-gate = h@Whh_n + b_hh_n -> bufC
        gemm_f16<<<gg, 256, 0, stream>>>(h_bf, Whht + 2 * HH, nullptr, nullptr,
                                         nullptr, b_hh + 2 * HID,
                                         nullptr, nullptr, nullptr, nullptr,
                                         bufC, nullptr, N_NODES, HID, 0);
        // h = relu((1-z)*tanh(msg@Wih_n + b_ih_n + r*hn) + z*h)  (fp32 + fp16)
        gemm_f16<<<gg, 256, 0, stream>>>(msg, Wiht + 2 * HH, nullptr, nullptr,
                                         nullptr, b_ih + 2 * HID,
                                         bufA, bufB, bufC, h_f32,
                                         h_bf, nullptr, N_NODES, HID, 2);
    }

    // ---- readout (fp32) ----
    {
        dim3 gm(HID / 256, 10);
        k_colmax<<<gm, 256, 0, stream>>>(h_f32, hmax);
    }
    k_r1<<<HID / 256, 256, 0, stream>>>(hmax, W_r1, b_r1, t1);
    k_r2<<<1, 256, 0, stream>>>(t1, W_r2, b_r2, out);
}

// Round 4
// 3280.718 us; speedup vs baseline: 5.7240x; 1.1462x over previous
//
#include <hip/hip_runtime.h>
#include <hip/hip_bf16.h>
#include <math.h>

#define N_NODES 10000
#define N_EDGES 160000
#define IN_DIM  512
#define HID     1024
#define M_PAD   10112   // 79 * 128

typedef _Float16 half8 __attribute__((ext_vector_type(8)));
typedef float    floatx4 __attribute__((ext_vector_type(4)));

__device__ inline void gld16(const void* g, void* l) {
    __builtin_amdgcn_global_load_lds(
        (const __attribute__((address_space(1))) unsigned int*)g,
        (__attribute__((address_space(3))) unsigned int*)l, 16, 0, 0);
}

__device__ inline float sig_(float x)  { return 1.0f / (1.0f + __expf(-x)); }
__device__ inline float tanh_(float x) { return 2.0f / (1.0f + __expf(-2.0f * x)) - 1.0f; }

// ---------------------------------------------------------------------------
// CSR build
// ---------------------------------------------------------------------------
__global__ void k_hist(const int* __restrict__ ei, int* __restrict__ deg, int ne) {
    int e = blockIdx.x * blockDim.x + threadIdx.x;
    if (e < ne) atomicAdd(&deg[ei[2 * e + 1]], 1);
}

__global__ void k_scan(const int* __restrict__ deg, int* __restrict__ offs, int n) {
    __shared__ int s[1024];
    __shared__ int base_s;
    int t = threadIdx.x;
    if (t == 0) base_s = 0;
    __syncthreads();
    int nchunk = (n + 1023) / 1024;
    for (int ch = 0; ch < nchunk; ++ch) {
        int i = ch * 1024 + t;
        int v = (i < n) ? deg[i] : 0;
        s[t] = v;
        __syncthreads();
        for (int off = 1; off < 1024; off <<= 1) {
            int add = (t >= off) ? s[t - off] : 0;
            __syncthreads();
            s[t] += add;
            __syncthreads();
        }
        int incl = s[t];
        int base = base_s;
        if (i < n) offs[i] = base + incl - v;   // exclusive
        __syncthreads();
        if (t == 1023) base_s = base + s[1023];
        __syncthreads();
    }
    if (t == 0) offs[n] = base_s;
}

__global__ void k_copy_int(const int* __restrict__ a, int* __restrict__ b, int n) {
    int i = blockIdx.x * blockDim.x + threadIdx.x;
    if (i < n) b[i] = a[i];
}

__global__ void k_scatter(const int* __restrict__ ei, const int* __restrict__ ed,
                          int* __restrict__ cur, int* __restrict__ esort, int ne) {
    int e = blockIdx.x * blockDim.x + threadIdx.x;
    if (e < ne) {
        int dst = ei[2 * e + 1];
        int pos = atomicAdd(&cur[dst], 1);
        esort[pos] = (ed[e] << 16) | ei[2 * e];
    }
}

// bias precompute: bfb = b_f + b_b ; brz = (b_ih + b_hh)[0:2H]
__global__ void k_prep(const float* __restrict__ b_f, const float* __restrict__ b_b,
                       const float* __restrict__ b_ih, const float* __restrict__ b_hh,
                       float* __restrict__ bfb, float* __restrict__ brz) {
    int i = blockIdx.x * blockDim.x + threadIdx.x;
    if (i < HID) bfb[i] = b_f[i] + b_b[i];
    if (i < 2 * HID) brz[i] = b_ih[i] + b_hh[i];
}

// fp32 KxN -> fp16 NxK transpose (weights)
__global__ __launch_bounds__(256) void k_transpose(const float* __restrict__ in,
                                                   _Float16* __restrict__ out,
                                                   int K, int N) {
    __shared__ float tile[32][33];
    int n0 = blockIdx.x * 32, k0 = blockIdx.y * 32;
    int tx = threadIdx.x & 31, ty = threadIdx.x >> 5;   // 32 x 8
#pragma unroll
    for (int r = 0; r < 4; ++r) {
        int k = k0 + ty + r * 8;
        tile[ty + r * 8][tx] = in[(size_t)k * N + n0 + tx];
    }
    __syncthreads();
#pragma unroll
    for (int r = 0; r < 4; ++r) {
        int n = n0 + ty + r * 8;
        out[(size_t)n * K + k0 + tx] = (_Float16)tile[tx][ty + r * 8];
    }
}

__global__ void k_cvt(const float* __restrict__ in, _Float16* __restrict__ out, int n) {
    int i = blockIdx.x * blockDim.x + threadIdx.x;
    if (i < n) out[i] = (_Float16)in[i];
}

// ---------------------------------------------------------------------------
// Aggregation: one block (128 thr) per node, 8 fp16 channels each (16B loads).
// ---------------------------------------------------------------------------
__global__ __launch_bounds__(128) void k_agg(
    const _Float16* __restrict__ h, const int* __restrict__ offs,
    const int* __restrict__ esort,
    _Float16* __restrict__ aggF, _Float16* __restrict__ aggB,
    _Float16* __restrict__ aggU) {
    int node = blockIdx.x;
    int c = threadIdx.x * 8;
    float f[8], b[8], u[8];
#pragma unroll
    for (int j = 0; j < 8; ++j) { f[j] = 0.f; b[j] = 0.f; u[j] = 0.f; }
    int beg = offs[node], end = offs[node + 1];
    for (int e = beg; e < end; ++e) {
        int pk = esort[e];
        int src = pk & 0xFFFF;
        int dir = pk >> 16;
        half8 v = *(const half8*)(h + (size_t)src * HID + c);
        if (dir == 0) {
#pragma unroll
            for (int j = 0; j < 8; ++j) f[j] += (float)v[j];
        } else if (dir == 1) {
#pragma unroll
            for (int j = 0; j < 8; ++j) b[j] += (float)v[j];
        } else {
#pragma unroll
            for (int j = 0; j < 8; ++j) u[j] += (float)v[j];
        }
    }
    size_t o = (size_t)node * HID + c;
    half8 vf, vb, vu;
#pragma unroll
    for (int j = 0; j < 8; ++j) {
        vf[j] = (_Float16)f[j]; vb[j] = (_Float16)b[j]; vu[j] = (_Float16)u[j];
    }
    *(half8*)(aggF + o) = vf;
    *(half8*)(aggB + o) = vb;
    *(half8*)(aggU + o) = vu;
}

// ---------------------------------------------------------------------------
// fp16 MFMA GEMM (generic): acc(f32) = A1@B1t^T [+ A2@B2t^T]
// epi 0: v = acc+bias [+U]; write Cbf [, Cf]
// epi 2: GRU: nn=tanh(acc+bias+R*HG); o=relu((1-Z)*nn+Z*Hf); Hf=o, Cbf=o
// 128x128 tile, BK=32, 256 thr = 4 waves of 4x4 mfma_f32_16x16x32_f16.
// ---------------------------------------------------------------------------
#define BM 128
#define BN 128
#define BK 32

__global__ __launch_bounds__(256) void gemm_f16(
    const _Float16* __restrict__ A1, const _Float16* __restrict__ B1t,
    const _Float16* __restrict__ A2, const _Float16* __restrict__ B2t,
    const _Float16* __restrict__ U, const float* __restrict__ bias,
    const _Float16* __restrict__ R, const _Float16* __restrict__ Zg,
    const _Float16* __restrict__ HG, float* __restrict__ Hf,
    _Float16* __restrict__ Cbf, float* __restrict__ Cf,
    int M, int K, int epi) {
    __shared__ _Float16 As[BM * BK];
    __shared__ _Float16 Bs[BN * BK];
    int t = threadIdx.x;
    int m0 = blockIdx.x * BM, n0 = blockIdx.y * BN;
    int wid = t >> 6, lane = t & 63;
    int wm = wid >> 1, wn = wid & 1;
    int quad = lane >> 4, mr = lane & 15;

    floatx4 acc[4][4] = {};

    int npair = (A2 != nullptr) ? 2 : 1;
    for (int p = 0; p < npair; ++p) {
        const _Float16* A = p ? A2 : A1;
        const _Float16* B = p ? B2t : B1t;
        for (int k0 = 0; k0 < K; k0 += BK) {
#pragma unroll
            for (int i = 0; i < 2; ++i) {
                int row = i * 64 + (t >> 2);
                int ce = (t & 3) * 8;
                gld16(A + (size_t)(m0 + row) * K + k0 + ce, As + i * 2048 + t * 8);
                gld16(B + (size_t)(n0 + row) * K + k0 + ce, Bs + i * 2048 + t * 8);
            }
            __syncthreads();
            half8 af[4], bfr[4];
#pragma unroll
            for (int i = 0; i < 4; ++i)
                af[i] = *(const half8*)(As + (wm * 64 + i * 16 + mr) * 32 + quad * 8);
#pragma unroll
            for (int j = 0; j < 4; ++j)
                bfr[j] = *(const half8*)(Bs + (wn * 64 + j * 16 + mr) * 32 + quad * 8);
#pragma unroll
            for (int i = 0; i < 4; ++i)
#pragma unroll
                for (int j = 0; j < 4; ++j)
                    acc[i][j] = __builtin_amdgcn_mfma_f32_16x16x32_f16(
                        af[i], bfr[j], acc[i][j], 0, 0, 0);
            __syncthreads();
        }
    }

#pragma unroll
    for (int i = 0; i < 4; ++i) {
#pragma unroll
        for (int j = 0; j < 4; ++j) {
            int n = n0 + wn * 64 + j * 16 + mr;
            float bv = bias[n];
#pragma unroll
            for (int r = 0; r < 4; ++r) {
                int m = m0 + wm * 64 + i * 16 + quad * 4 + r;
                if (m >= M) continue;
                size_t idx = (size_t)m * HID + n;
                float v = acc[i][j][r] + bv;
                if (epi == 0) {
                    if (U) v += (float)U[idx];
                    if (Cf) Cf[idx] = v;
                    Cbf[idx] = (_Float16)v;
                } else {
                    float rr = (float)R[idx], zz = (float)Zg[idx], hg = (float)HG[idx];
                    float hv = Hf[idx];
                    float nn = tanh_(v + rr * hg);
                    float o = fmaxf((1.f - zz) * nn + zz * hv, 0.f);
                    Hf[idx] = o;
                    Cbf[idx] = (_Float16)o;
                }
            }
        }
    }
}

// ---------------------------------------------------------------------------
// Fused gate GEMM over N=3072 of Wih^T / Whh^T (both 3072 x 1024, N x K):
//   y-tile n0 in [0,2048):  seg<2:  C = sigmoid(msg@Wih[n] + h@Whh[n] + brz[n])
//   y-tile n0 in [2048,3072): seg2: C = h@Whh[n] + b_hh[n]      (hn-gate)
// Writes r->bufA, z->bufB, hn->bufC (each M x 1024).
// ---------------------------------------------------------------------------
__global__ __launch_bounds__(256) void gemm_gates(
    const _Float16* __restrict__ msg, const _Float16* __restrict__ hbf,
    const _Float16* __restrict__ Wiht, const _Float16* __restrict__ Whht,
    const float* __restrict__ brz, const float* __restrict__ b_hh,
    _Float16* __restrict__ bufA, _Float16* __restrict__ bufB,
    _Float16* __restrict__ bufC, int M) {
    __shared__ _Float16 As[BM * BK];
    __shared__ _Float16 Bs[BN * BK];
    int t = threadIdx.x;
    int m0 = blockIdx.x * BM;
    int ng0 = blockIdx.y * BN;          // global n in [0, 3072)
    int seg = ng0 >> 10;                // 0=r, 1=z, 2=hn
    int wid = t >> 6, lane = t & 63;
    int wm = wid >> 1, wn = wid & 1;
    int quad = lane >> 4, mr = lane & 15;

    const _Float16* A1 = (seg < 2) ? msg : hbf;
    const _Float16* B1 = ((seg < 2) ? Wiht : Whht) + (size_t)ng0 * HID;
    const _Float16* A2 = hbf;
    const _Float16* B2 = Whht + (size_t)ng0 * HID;
    int npair = (seg < 2) ? 2 : 1;

    floatx4 acc[4][4] = {};
    for (int p = 0; p < npair; ++p) {
        const _Float16* A = p ? A2 : A1;
        const _Float16* B = p ? B2 : B1;
        for (int k0 = 0; k0 < HID; k0 += BK) {
#pragma unroll
            for (int i = 0; i < 2; ++i) {
                int row = i * 64 + (t >> 2);
                int ce = (t & 3) * 8;
                gld16(A + (size_t)(m0 + row) * HID + k0 + ce, As + i * 2048 + t * 8);
                gld16(B + (size_t)row * HID + k0 + ce, Bs + i * 2048 + t * 8);
            }
            __syncthreads();
            half8 af[4], bfr[4];
#pragma unroll
            for (int i = 0; i < 4; ++i)
                af[i] = *(const half8*)(As + (wm * 64 + i * 16 + mr) * 32 + quad * 8);
#pragma unroll
            for (int j = 0; j < 4; ++j)
                bfr[j] = *(const half8*)(Bs + (wn * 64 + j * 16 + mr) * 32 + quad * 8);
#pragma unroll
            for (int i = 0; i < 4; ++i)
#pragma unroll
                for (int j = 0; j < 4; ++j)
                    acc[i][j] = __builtin_amdgcn_mfma_f32_16x16x32_f16(
                        af[i], bfr[j], acc[i][j], 0, 0, 0);
            __syncthreads();
        }
    }

    _Float16* Cb = (seg == 0) ? bufA : (seg == 1) ? bufB : bufC;
#pragma unroll
    for (int i = 0; i < 4; ++i) {
#pragma unroll
        for (int j = 0; j < 4; ++j) {
            int n = ng0 + wn * 64 + j * 16 + mr;       // global [0,3072)
            int nloc = n & 1023;
            float bv = (seg < 2) ? brz[n] : b_hh[n];
#pragma unroll
            for (int r = 0; r < 4; ++r) {
                int m = m0 + wm * 64 + i * 16 + quad * 4 + r;
                if (m >= M) continue;
                size_t idx = (size_t)m * HID + nloc;
                float v = acc[i][j][r] + bv;
                Cb[idx] = (_Float16)((seg < 2) ? sig_(v) : v);
            }
        }
    }
}

// ---------------------------------------------------------------------------
// Readout (fp32)
// ---------------------------------------------------------------------------
__global__ void k_colmax(const float* __restrict__ h, float* __restrict__ hmax) {
    int c = blockIdx.x * blockDim.x + threadIdx.x;
    int r0 = blockIdx.y * 200;
    int r1 = r0 + 200; if (r1 > N_NODES) r1 = N_NODES;
    float m = 0.f;                                      // h >= 0 post-relu
    for (int r = r0; r < r1; ++r)
        m = fmaxf(m, h[(size_t)r * HID + c]);
    atomicMax((int*)&hmax[c], __float_as_int(m));       // valid for floats >= 0
}

__global__ void k_r1(const float* __restrict__ hmax, const float* __restrict__ W,
                     const float* __restrict__ b, float* __restrict__ t1) {
    int j = blockIdx.x * blockDim.x + threadIdx.x;
    if (j >= HID) return;
    float acc = b[j];
    for (int k = 0; k < HID; ++k) acc += hmax[k] * W[(size_t)k * HID + j];
    t1[j] = fmaxf(acc, 0.f);
}

__global__ void k_r2(const float* __restrict__ t1, const float* __restrict__ W2,
                     const float* __restrict__ b2, float* __restrict__ out) {
    __shared__ float s[256];
    int t = threadIdx.x;
    float acc = 0.f;
    for (int i = t; i < HID; i += 256) acc += t1[i] * W2[i];
    s[t] = acc;
    __syncthreads();
    for (int st = 128; st > 0; st >>= 1) {
        if (t < st) s[t] += s[t + st];
        __syncthreads();
    }
    if (t == 0) out[0] = s[0] + b2[0];
}

// ---------------------------------------------------------------------------
extern "C" void kernel_launch(void* const* d_in, const int* in_sizes, int n_in,
                              void* d_out, int out_size, void* d_ws, size_t ws_size,
                              hipStream_t stream) {
    const float* node_features = (const float*)d_in[0];
    const int*   edge_index    = (const int*)d_in[1];
    const int*   edge_dirs     = (const int*)d_in[2];
    const float* W_in = (const float*)d_in[3];
    const float* b_in = (const float*)d_in[4];
    const float* W_f  = (const float*)d_in[5];
    const float* b_f  = (const float*)d_in[6];
    const float* W_b  = (const float*)d_in[7];
    const float* b_b  = (const float*)d_in[8];
    const float* W_ih = (const float*)d_in[9];
    const float* b_ih = (const float*)d_in[10];
    const float* W_hh = (const float*)d_in[11];
    const float* b_hh = (const float*)d_in[12];
    const float* W_r1 = (const float*)d_in[13];
    const float* b_r1 = (const float*)d_in[14];
    const float* W_r2 = (const float*)d_in[15];
    const float* b_r2 = (const float*)d_in[16];
    float* out = (float*)d_out;

    // ---- workspace layout ----
    float* ws = (float*)d_ws;
    size_t off = 0;
    auto allocf = [&](size_t n) { float* p = ws + off; off += n; return p; };
    const size_t PH = (size_t)M_PAD * HID;
    float* h_f32 = allocf(PH);          // fp32 GRU state
    float* bfb   = allocf(HID);
    float* brz   = allocf(2 * HID);
    float* hmax  = allocf(HID);
    float* t1    = allocf(HID);
    _Float16* hp = (_Float16*)(ws + off);
    size_t hoff = 0;
    auto alloch = [&](size_t n) { _Float16* p = hp + hoff; hoff += n; return p; };
    _Float16* h_bf  = alloch(PH);       // fp16 shadow of h
    _Float16* msg   = alloch(PH);
    _Float16* bufA  = alloch(PH);       // aggF -> r
    _Float16* bufB  = alloch(PH);       // aggB -> z
    _Float16* bufC  = alloch(PH);       // aggU -> hn-gate
    _Float16* X_bf  = alloch((size_t)M_PAD * IN_DIM);
    _Float16* Wint  = alloch((size_t)HID * IN_DIM);
    _Float16* Wft   = alloch((size_t)HID * HID);
    _Float16* Wbt   = alloch((size_t)HID * HID);
    _Float16* Wiht  = alloch((size_t)3 * HID * HID);   // 3072 x 1024 (N x K)
    _Float16* Whht  = alloch((size_t)3 * HID * HID);
    int* ibase = (int*)(hp + hoff);
    int* deg   = ibase;
    int* offs  = ibase + N_NODES;
    int* cur   = offs + N_NODES + 1;
    int* esort = cur + N_NODES;

    // ---- CSR build + prep ----
    hipMemsetAsync(deg, 0, N_NODES * sizeof(int), stream);
    hipMemsetAsync(hmax, 0, HID * sizeof(float), stream);
    k_hist<<<(N_EDGES + 255) / 256, 256, 0, stream>>>(edge_index, deg, N_EDGES);
    k_scan<<<1, 1024, 0, stream>>>(deg, offs, N_NODES);
    k_copy_int<<<(N_NODES + 255) / 256, 256, 0, stream>>>(offs, cur, N_NODES);
    k_scatter<<<(N_EDGES + 255) / 256, 256, 0, stream>>>(edge_index, edge_dirs, cur,
                                                         esort, N_EDGES);
    k_prep<<<8, 256, 0, stream>>>(b_f, b_b, b_ih, b_hh, bfb, brz);

    k_transpose<<<dim3(HID / 32, IN_DIM / 32), 256, 0, stream>>>(W_in, Wint, IN_DIM, HID);
    k_transpose<<<dim3(HID / 32, HID / 32), 256, 0, stream>>>(W_f, Wft, HID, HID);
    k_transpose<<<dim3(HID / 32, HID / 32), 256, 0, stream>>>(W_b, Wbt, HID, HID);
    k_transpose<<<dim3(3 * HID / 32, HID / 32), 256, 0, stream>>>(W_ih, Wiht, HID, 3 * HID);
    k_transpose<<<dim3(3 * HID / 32, HID / 32), 256, 0, stream>>>(W_hh, Whht, HID, 3 * HID);
    k_cvt<<<(N_NODES * IN_DIM + 255) / 256, 256, 0, stream>>>(node_features, X_bf,
                                                              N_NODES * IN_DIM);

    dim3 gg(M_PAD / BM, HID / BN);        // 79 x 8
    dim3 gg3(M_PAD / BM, 3 * HID / BN);   // 79 x 24

    // ---- input projection ----
    gemm_f16<<<gg, 256, 0, stream>>>(X_bf, Wint, nullptr, nullptr,
                                     nullptr, b_in, nullptr, nullptr, nullptr,
                                     nullptr, h_bf, h_f32, N_NODES, IN_DIM, 0);

    const size_t HH = (size_t)HID * HID;
    for (int layer = 0; layer < 8; ++layer) {
        k_agg<<<N_NODES, 128, 0, stream>>>(h_bf, offs, esort, bufA, bufB, bufC);
        // msg = aggF@W_f + aggB@W_b + aggU + (b_f+b_b)
        gemm_f16<<<gg, 256, 0, stream>>>(bufA, Wft, bufB, Wbt, bufC, bfb,
                                         nullptr, nullptr, nullptr, nullptr,
                                         msg, nullptr, N_NODES, HID, 0);
        // r,z,hn fused over N=3072 -> bufA, bufB, bufC
        gemm_gates<<<gg3, 256, 0, stream>>>(msg, h_bf, Wiht, Whht, brz, b_hh,
                                            bufA, bufB, bufC, N_NODES);
        // h = relu((1-z)*tanh(msg@Wih_n + b_ih_n + r*hn) + z*h)
        gemm_f16<<<gg, 256, 0, stream>>>(msg, Wiht + 2 * HH, nullptr, nullptr,
                                         nullptr, b_ih + 2 * HID,
                                         bufA, bufB, bufC, h_f32,
                                         h_bf, nullptr, N_NODES, HID, 2);
    }

    // ---- readout (fp32) ----
    {
        dim3 gm(HID / 256, 50);
        k_colmax<<<gm, 256, 0, stream>>>(h_f32, hmax);
    }
    k_r1<<<HID / 256, 256, 0, stream>>>(hmax, W_r1, b_r1, t1);
    k_r2<<<1, 256, 0, stream>>>(t1, W_r2, b_r2, out);
}

// Round 5
// 3175.877 us; speedup vs baseline: 5.9129x; 1.0330x over previous
//
#include <hip/hip_runtime.h>
#include <hip/hip_bf16.h>
#include <math.h>

#define N_NODES 10000
#define N_EDGES 160000
#define IN_DIM  512
#define HID     1024
#define M_PAD   10112   // 79 * 128

typedef _Float16 half8 __attribute__((ext_vector_type(8)));
typedef float    floatx4 __attribute__((ext_vector_type(4)));

__device__ inline void gld16(const void* g, void* l) {
    __builtin_amdgcn_global_load_lds(
        (const __attribute__((address_space(1))) unsigned int*)g,
        (__attribute__((address_space(3))) unsigned int*)l, 16, 0, 0);
}

__device__ inline float sig_(float x)  { return 1.0f / (1.0f + __expf(-x)); }
__device__ inline float tanh_(float x) { return 2.0f / (1.0f + __expf(-2.0f * x)) - 1.0f; }

// ---------------------------------------------------------------------------
// CSR build
// ---------------------------------------------------------------------------
__global__ void k_hist(const int* __restrict__ ei, int* __restrict__ deg, int ne) {
    int e = blockIdx.x * blockDim.x + threadIdx.x;
    if (e < ne) atomicAdd(&deg[ei[2 * e + 1]], 1);
}

__global__ void k_scan(const int* __restrict__ deg, int* __restrict__ offs, int n) {
    __shared__ int s[1024];
    __shared__ int base_s;
    int t = threadIdx.x;
    if (t == 0) base_s = 0;
    __syncthreads();
    int nchunk = (n + 1023) / 1024;
    for (int ch = 0; ch < nchunk; ++ch) {
        int i = ch * 1024 + t;
        int v = (i < n) ? deg[i] : 0;
        s[t] = v;
        __syncthreads();
        for (int off = 1; off < 1024; off <<= 1) {
            int add = (t >= off) ? s[t - off] : 0;
            __syncthreads();
            s[t] += add;
            __syncthreads();
        }
        int incl = s[t];
        int base = base_s;
        if (i < n) offs[i] = base + incl - v;   // exclusive
        __syncthreads();
        if (t == 1023) base_s = base + s[1023];
        __syncthreads();
    }
    if (t == 0) offs[n] = base_s;
}

__global__ void k_copy_int(const int* __restrict__ a, int* __restrict__ b, int n) {
    int i = blockIdx.x * blockDim.x + threadIdx.x;
    if (i < n) b[i] = a[i];
}

__global__ void k_scatter(const int* __restrict__ ei, const int* __restrict__ ed,
                          int* __restrict__ cur, int* __restrict__ esort, int ne) {
    int e = blockIdx.x * blockDim.x + threadIdx.x;
    if (e < ne) {
        int dst = ei[2 * e + 1];
        int pos = atomicAdd(&cur[dst], 1);
        esort[pos] = (ed[e] << 16) | ei[2 * e];
    }
}

// bias precompute: bfb = b_f + b_b ; brz = (b_ih + b_hh)[0:2H]
__global__ void k_prep(const float* __restrict__ b_f, const float* __restrict__ b_b,
                       const float* __restrict__ b_ih, const float* __restrict__ b_hh,
                       float* __restrict__ bfb, float* __restrict__ brz) {
    int i = blockIdx.x * blockDim.x + threadIdx.x;
    if (i < HID) bfb[i] = b_f[i] + b_b[i];
    if (i < 2 * HID) brz[i] = b_ih[i] + b_hh[i];
}

// fp32 KxN -> fp16 NxK transpose (weights)
__global__ __launch_bounds__(256) void k_transpose(const float* __restrict__ in,
                                                   _Float16* __restrict__ out,
                                                   int K, int N) {
    __shared__ float tile[32][33];
    int n0 = blockIdx.x * 32, k0 = blockIdx.y * 32;
    int tx = threadIdx.x & 31, ty = threadIdx.x >> 5;   // 32 x 8
#pragma unroll
    for (int r = 0; r < 4; ++r) {
        int k = k0 + ty + r * 8;
        tile[ty + r * 8][tx] = in[(size_t)k * N + n0 + tx];
    }
    __syncthreads();
#pragma unroll
    for (int r = 0; r < 4; ++r) {
        int n = n0 + ty + r * 8;
        out[(size_t)n * K + k0 + tx] = (_Float16)tile[tx][ty + r * 8];
    }
}

__global__ void k_cvt(const float* __restrict__ in, _Float16* __restrict__ out, int n) {
    int i = blockIdx.x * blockDim.x + threadIdx.x;
    if (i < n) out[i] = (_Float16)in[i];
}

// ---------------------------------------------------------------------------
// Aggregation: one block (128 thr) per node, 8 fp16 channels each (16B loads).
// ---------------------------------------------------------------------------
__global__ __launch_bounds__(128) void k_agg(
    const _Float16* __restrict__ h, const int* __restrict__ offs,
    const int* __restrict__ esort,
    _Float16* __restrict__ aggF, _Float16* __restrict__ aggB,
    _Float16* __restrict__ aggU) {
    int node = blockIdx.x;
    int c = threadIdx.x * 8;
    float f[8], b[8], u[8];
#pragma unroll
    for (int j = 0; j < 8; ++j) { f[j] = 0.f; b[j] = 0.f; u[j] = 0.f; }
    int beg = offs[node], end = offs[node + 1];
    for (int e = beg; e < end; ++e) {
        int pk = esort[e];
        int src = pk & 0xFFFF;
        int dir = pk >> 16;
        half8 v = *(const half8*)(h + (size_t)src * HID + c);
        if (dir == 0) {
#pragma unroll
            for (int j = 0; j < 8; ++j) f[j] += (float)v[j];
        } else if (dir == 1) {
#pragma unroll
            for (int j = 0; j < 8; ++j) b[j] += (float)v[j];
        } else {
#pragma unroll
            for (int j = 0; j < 8; ++j) u[j] += (float)v[j];
        }
    }
    size_t o = (size_t)node * HID + c;
    half8 vf, vb, vu;
#pragma unroll
    for (int j = 0; j < 8; ++j) {
        vf[j] = (_Float16)f[j]; vb[j] = (_Float16)b[j]; vu[j] = (_Float16)u[j];
    }
    *(half8*)(aggF + o) = vf;
    *(half8*)(aggB + o) = vb;
    *(half8*)(aggU + o) = vu;
}

// ---------------------------------------------------------------------------
// fp16 MFMA GEMM, 128x256 tile, BK=32, 512 thr = 8 waves (2m x 4n), each wave
// a 64x64 microtile of 4x4 mfma_f32_16x16x32_f16. Output width fixed = HID.
// epi 0: v = acc+bias [+U]; write Cbf [, Cf]
// epi 2: GRU: nn=tanh(acc+bias+R*HG); o=relu((1-Z)*nn+Z*Hf); Hf=o, Cbf=o
// ---------------------------------------------------------------------------
#define BM 128
#define BN 256
#define BK 32
#define NTHR 512

__global__ __launch_bounds__(NTHR) void gemm_f16(
    const _Float16* __restrict__ A1, const _Float16* __restrict__ B1t,
    const _Float16* __restrict__ A2, const _Float16* __restrict__ B2t,
    const _Float16* __restrict__ U, const float* __restrict__ bias,
    const _Float16* __restrict__ R, const _Float16* __restrict__ Zg,
    const _Float16* __restrict__ HG, float* __restrict__ Hf,
    _Float16* __restrict__ Cbf, float* __restrict__ Cf,
    int M, int K, int epi) {
    __shared__ _Float16 As[BM * BK];   // 8 KB
    __shared__ _Float16 Bs[BN * BK];   // 16 KB
    int t = threadIdx.x;
    int m0 = blockIdx.x * BM, n0 = blockIdx.y * BN;
    int wid = t >> 6, lane = t & 63;
    int wm = wid & 1, wn = wid >> 1;            // 2 x 4 wave grid
    int quad = lane >> 4, mr = lane & 15;

    floatx4 acc[4][4] = {};

    int npair = (A2 != nullptr) ? 2 : 1;
    for (int p = 0; p < npair; ++p) {
        const _Float16* A = p ? A2 : A1;
        const _Float16* B = p ? B2t : B1t;
        for (int k0 = 0; k0 < K; k0 += BK) {
            {   // A tile 128x32: 1 gld16 per thread
                int row = t >> 2;
                int ce = (t & 3) * 8;
                gld16(A + (size_t)(m0 + row) * K + k0 + ce, As + t * 8);
            }
#pragma unroll
            for (int i = 0; i < 2; ++i) {       // B tile 256x32: 2 gld16
                int row = i * 128 + (t >> 2);
                int ce = (t & 3) * 8;
                gld16(B + (size_t)(n0 + row) * K + k0 + ce, Bs + i * 4096 + t * 8);
            }
            __syncthreads();
            half8 af[4], bfr[4];
#pragma unroll
            for (int i = 0; i < 4; ++i)
                af[i] = *(const half8*)(As + (wm * 64 + i * 16 + mr) * 32 + quad * 8);
#pragma unroll
            for (int j = 0; j < 4; ++j)
                bfr[j] = *(const half8*)(Bs + (wn * 64 + j * 16 + mr) * 32 + quad * 8);
#pragma unroll
            for (int i = 0; i < 4; ++i)
#pragma unroll
                for (int j = 0; j < 4; ++j)
                    acc[i][j] = __builtin_amdgcn_mfma_f32_16x16x32_f16(
                        af[i], bfr[j], acc[i][j], 0, 0, 0);
            __syncthreads();
        }
    }

#pragma unroll
    for (int i = 0; i < 4; ++i) {
#pragma unroll
        for (int j = 0; j < 4; ++j) {
            int n = n0 + wn * 64 + j * 16 + mr;
            float bv = bias[n];
#pragma unroll
            for (int r = 0; r < 4; ++r) {
                int m = m0 + wm * 64 + i * 16 + quad * 4 + r;
                if (m >= M) continue;
                size_t idx = (size_t)m * HID + n;
                float v = acc[i][j][r] + bv;
                if (epi == 0) {
                    if (U) v += (float)U[idx];
                    if (Cf) Cf[idx] = v;
                    Cbf[idx] = (_Float16)v;
                } else {
                    float rr = (float)R[idx], zz = (float)Zg[idx], hg = (float)HG[idx];
                    float hv = Hf[idx];
                    float nn = tanh_(v + rr * hg);
                    float o = fmaxf((1.f - zz) * nn + zz * hv, 0.f);
                    Hf[idx] = o;
                    Cbf[idx] = (_Float16)o;
                }
            }
        }
    }
}

// ---------------------------------------------------------------------------
// Fused gate GEMM over N=3072 of Wih^T / Whh^T (both 3072 x 1024, N x K):
//   ng0 in [0,2048):   C = sigmoid(msg@Wih[n] + h@Whh[n] + brz[n])  (r, z)
//   ng0 in [2048,3072): C = h@Whh[n] + b_hh[n]                      (hn-gate)
// Writes r->bufA, z->bufB, hn->bufC (each M x 1024).
// ---------------------------------------------------------------------------
__global__ __launch_bounds__(NTHR) void gemm_gates(
    const _Float16* __restrict__ msg, const _Float16* __restrict__ hbf,
    const _Float16* __restrict__ Wiht, const _Float16* __restrict__ Whht,
    const float* __restrict__ brz, const float* __restrict__ b_hh,
    _Float16* __restrict__ bufA, _Float16* __restrict__ bufB,
    _Float16* __restrict__ bufC, int M) {
    __shared__ _Float16 As[BM * BK];
    __shared__ _Float16 Bs[BN * BK];
    int t = threadIdx.x;
    int m0 = blockIdx.x * BM;
    int ng0 = blockIdx.y * BN;          // global n in [0, 3072), 256-aligned
    int seg = ng0 >> 10;                // 0=r, 1=z, 2=hn
    int wid = t >> 6, lane = t & 63;
    int wm = wid & 1, wn = wid >> 1;
    int quad = lane >> 4, mr = lane & 15;

    const _Float16* A1 = (seg < 2) ? msg : hbf;
    const _Float16* B1 = ((seg < 2) ? Wiht : Whht) + (size_t)ng0 * HID;
    const _Float16* A2 = hbf;
    const _Float16* B2 = Whht + (size_t)ng0 * HID;
    int npair = (seg < 2) ? 2 : 1;

    floatx4 acc[4][4] = {};
    for (int p = 0; p < npair; ++p) {
        const _Float16* A = p ? A2 : A1;
        const _Float16* B = p ? B2 : B1;
        for (int k0 = 0; k0 < HID; k0 += BK) {
            {
                int row = t >> 2;
                int ce = (t & 3) * 8;
                gld16(A + (size_t)(m0 + row) * HID + k0 + ce, As + t * 8);
            }
#pragma unroll
            for (int i = 0; i < 2; ++i) {
                int row = i * 128 + (t >> 2);
                int ce = (t & 3) * 8;
                gld16(B + (size_t)row * HID + k0 + ce, Bs + i * 4096 + t * 8);
            }
            __syncthreads();
            half8 af[4], bfr[4];
#pragma unroll
            for (int i = 0; i < 4; ++i)
                af[i] = *(const half8*)(As + (wm * 64 + i * 16 + mr) * 32 + quad * 8);
#pragma unroll
            for (int j = 0; j < 4; ++j)
                bfr[j] = *(const half8*)(Bs + (wn * 64 + j * 16 + mr) * 32 + quad * 8);
#pragma unroll
            for (int i = 0; i < 4; ++i)
#pragma unroll
                for (int j = 0; j < 4; ++j)
                    acc[i][j] = __builtin_amdgcn_mfma_f32_16x16x32_f16(
                        af[i], bfr[j], acc[i][j], 0, 0, 0);
            __syncthreads();
        }
    }

    _Float16* Cb = (seg == 0) ? bufA : (seg == 1) ? bufB : bufC;
#pragma unroll
    for (int i = 0; i < 4; ++i) {
#pragma unroll
        for (int j = 0; j < 4; ++j) {
            int n = ng0 + wn * 64 + j * 16 + mr;       // global [0,3072)
            int nloc = n & 1023;
            float bv = (seg < 2) ? brz[n] : b_hh[n];
#pragma unroll
            for (int r = 0; r < 4; ++r) {
                int m = m0 + wm * 64 + i * 16 + quad * 4 + r;
                if (m >= M) continue;
                size_t idx = (size_t)m * HID + nloc;
                float v = acc[i][j][r] + bv;
                Cb[idx] = (_Float16)((seg < 2) ? sig_(v) : v);
            }
        }
    }
}

// ---------------------------------------------------------------------------
// Readout (fp32)
// ---------------------------------------------------------------------------
__global__ void k_colmax(const float* __restrict__ h, float* __restrict__ hmax) {
    int c = blockIdx.x * blockDim.x + threadIdx.x;
    int r0 = blockIdx.y * 200;
    int r1 = r0 + 200; if (r1 > N_NODES) r1 = N_NODES;
    float m = 0.f;                                      // h >= 0 post-relu
    for (int r = r0; r < r1; ++r)
        m = fmaxf(m, h[(size_t)r * HID + c]);
    atomicMax((int*)&hmax[c], __float_as_int(m));       // valid for floats >= 0
}

__global__ void k_r1(const float* __restrict__ hmax, const float* __restrict__ W,
                     const float* __restrict__ b, float* __restrict__ t1) {
    int j = blockIdx.x * blockDim.x + threadIdx.x;
    if (j >= HID) return;
    float acc = b[j];
    for (int k = 0; k < HID; ++k) acc += hmax[k] * W[(size_t)k * HID + j];
    t1[j] = fmaxf(acc, 0.f);
}

__global__ void k_r2(const float* __restrict__ t1, const float* __restrict__ W2,
                     const float* __restrict__ b2, float* __restrict__ out) {
    __shared__ float s[256];
    int t = threadIdx.x;
    float acc = 0.f;
    for (int i = t; i < HID; i += 256) acc += t1[i] * W2[i];
    s[t] = acc;
    __syncthreads();
    for (int st = 128; st > 0; st >>= 1) {
        if (t < st) s[t] += s[t + st];
        __syncthreads();
    }
    if (t == 0) out[0] = s[0] + b2[0];
}

// ---------------------------------------------------------------------------
extern "C" void kernel_launch(void* const* d_in, const int* in_sizes, int n_in,
                              void* d_out, int out_size, void* d_ws, size_t ws_size,
                              hipStream_t stream) {
    const float* node_features = (const float*)d_in[0];
    const int*   edge_index    = (const int*)d_in[1];
    const int*   edge_dirs     = (const int*)d_in[2];
    const float* W_in = (const float*)d_in[3];
    const float* b_in = (const float*)d_in[4];
    const float* W_f  = (const float*)d_in[5];
    const float* b_f  = (const float*)d_in[6];
    const float* W_b  = (const float*)d_in[7];
    const float* b_b  = (const float*)d_in[8];
    const float* W_ih = (const float*)d_in[9];
    const float* b_ih = (const float*)d_in[10];
    const float* W_hh = (const float*)d_in[11];
    const float* b_hh = (const float*)d_in[12];
    const float* W_r1 = (const float*)d_in[13];
    const float* b_r1 = (const float*)d_in[14];
    const float* W_r2 = (const float*)d_in[15];
    const float* b_r2 = (const float*)d_in[16];
    float* out = (float*)d_out;

    // ---- workspace layout ----
    float* ws = (float*)d_ws;
    size_t off = 0;
    auto allocf = [&](size_t n) { float* p = ws + off; off += n; return p; };
    const size_t PH = (size_t)M_PAD * HID;
    float* h_f32 = allocf(PH);          // fp32 GRU state
    float* bfb   = allocf(HID);
    float* brz   = allocf(2 * HID);
    float* hmax  = allocf(HID);
    float* t1    = allocf(HID);
    _Float16* hp = (_Float16*)(ws + off);
    size_t hoff = 0;
    auto alloch = [&](size_t n) { _Float16* p = hp + hoff; hoff += n; return p; };
    _Float16* h_bf  = alloch(PH);       // fp16 shadow of h
    _Float16* msg   = alloch(PH);
    _Float16* bufA  = alloch(PH);       // aggF -> r
    _Float16* bufB  = alloch(PH);       // aggB -> z
    _Float16* bufC  = alloch(PH);       // aggU -> hn-gate
    _Float16* X_bf  = alloch((size_t)M_PAD * IN_DIM);
    _Float16* Wint  = alloch((size_t)HID * IN_DIM);
    _Float16* Wft   = alloch((size_t)HID * HID);
    _Float16* Wbt   = alloch((size_t)HID * HID);
    _Float16* Wiht  = alloch((size_t)3 * HID * HID);   // 3072 x 1024 (N x K)
    _Float16* Whht  = alloch((size_t)3 * HID * HID);
    int* ibase = (int*)(hp + hoff);
    int* deg   = ibase;
    int* offs  = ibase + N_NODES;
    int* cur   = offs + N_NODES + 1;
    int* esort = cur + N_NODES;

    // ---- CSR build + prep ----
    hipMemsetAsync(deg, 0, N_NODES * sizeof(int), stream);
    hipMemsetAsync(hmax, 0, HID * sizeof(float), stream);
    k_hist<<<(N_EDGES + 255) / 256, 256, 0, stream>>>(edge_index, deg, N_EDGES);
    k_scan<<<1, 1024, 0, stream>>>(deg, offs, N_NODES);
    k_copy_int<<<(N_NODES + 255) / 256, 256, 0, stream>>>(offs, cur, N_NODES);
    k_scatter<<<(N_EDGES + 255) / 256, 256, 0, stream>>>(edge_index, edge_dirs, cur,
                                                         esort, N_EDGES);
    k_prep<<<8, 256, 0, stream>>>(b_f, b_b, b_ih, b_hh, bfb, brz);

    k_transpose<<<dim3(HID / 32, IN_DIM / 32), 256, 0, stream>>>(W_in, Wint, IN_DIM, HID);
    k_transpose<<<dim3(HID / 32, HID / 32), 256, 0, stream>>>(W_f, Wft, HID, HID);
    k_transpose<<<dim3(HID / 32, HID / 32), 256, 0, stream>>>(W_b, Wbt, HID, HID);
    k_transpose<<<dim3(3 * HID / 32, HID / 32), 256, 0, stream>>>(W_ih, Wiht, HID, 3 * HID);
    k_transpose<<<dim3(3 * HID / 32, HID / 32), 256, 0, stream>>>(W_hh, Whht, HID, 3 * HID);
    k_cvt<<<(N_NODES * IN_DIM + 255) / 256, 256, 0, stream>>>(node_features, X_bf,
                                                              N_NODES * IN_DIM);

    dim3 gg(M_PAD / BM, HID / BN);        // 79 x 4
    dim3 gg3(M_PAD / BM, 3 * HID / BN);   // 79 x 12

    // ---- input projection ----
    gemm_f16<<<gg, NTHR, 0, stream>>>(X_bf, Wint, nullptr, nullptr,
                                      nullptr, b_in, nullptr, nullptr, nullptr,
                                      nullptr, h_bf, h_f32, N_NODES, IN_DIM, 0);

    const size_t HH = (size_t)HID * HID;
    for (int layer = 0; layer < 8; ++layer) {
        k_agg<<<N_NODES, 128, 0, stream>>>(h_bf, offs, esort, bufA, bufB, bufC);
        // msg = aggF@W_f + aggB@W_b + aggU + (b_f+b_b)
        gemm_f16<<<gg, NTHR, 0, stream>>>(bufA, Wft, bufB, Wbt, bufC, bfb,
                                          nullptr, nullptr, nullptr, nullptr,
                                          msg, nullptr, N_NODES, HID, 0);
        // r,z,hn fused over N=3072 -> bufA, bufB, bufC
        gemm_gates<<<gg3, NTHR, 0, stream>>>(msg, h_bf, Wiht, Whht, brz, b_hh,
                                             bufA, bufB, bufC, N_NODES);
        // h = relu((1-z)*tanh(msg@Wih_n + b_ih_n + r*hn) + z*h)
        gemm_f16<<<gg, NTHR, 0, stream>>>(msg, Wiht + 2 * HH, nullptr, nullptr,
                                          nullptr, b_ih + 2 * HID,
                                          bufA, bufB, bufC, h_f32,
                                          h_bf, nullptr, N_NODES, HID, 2);
    }

    // ---- readout (fp32) ----
    {
        dim3 gm(HID / 256, 50);
        k_colmax<<<gm, 256, 0, stream>>>(h_f32, hmax);
    }
    k_r1<<<HID / 256, 256, 0, stream>>>(hmax, W_r1, b_r1, t1);
    k_r2<<<1, 256, 0, stream>>>(t1, W_r2, b_r2, out);
}

// Round 6
// 3137.806 us; speedup vs baseline: 5.9847x; 1.0121x over previous
//
#include <hip/hip_runtime.h>
#include <hip/hip_bf16.h>
#include <math.h>

#define N_NODES 10000
#define N_EDGES 160000
#define IN_DIM  512
#define HID     1024
#define M_PAD   10112   // 79 * 128

typedef _Float16 half8 __attribute__((ext_vector_type(8)));
typedef float    floatx4 __attribute__((ext_vector_type(4)));

__device__ inline void gld16(const void* g, void* l) {
    __builtin_amdgcn_global_load_lds(
        (const __attribute__((address_space(1))) unsigned int*)g,
        (__attribute__((address_space(3))) unsigned int*)l, 16, 0, 0);
}

__device__ inline float sig_(float x)  { return 1.0f / (1.0f + __expf(-x)); }
__device__ inline float tanh_(float x) { return 2.0f / (1.0f + __expf(-2.0f * x)) - 1.0f; }

// Supertile swizzle: 4 consecutive linear block ids share one x (A-tile),
// covering 4 y (weight slices); then x advances. Requires gridDim.y % 4 == 0.
__device__ inline void swizzle_xy(int& bx, int& by) {
    int lin = blockIdx.y * gridDim.x + blockIdx.x;
    int per = gridDim.x << 2;
    int sup = lin / per;
    int rem = lin - sup * per;
    by = (sup << 2) + (rem & 3);
    bx = rem >> 2;
}

// ---------------------------------------------------------------------------
// CSR build
// ---------------------------------------------------------------------------
__global__ void k_hist(const int* __restrict__ ei, int* __restrict__ deg, int ne) {
    int e = blockIdx.x * blockDim.x + threadIdx.x;
    if (e < ne) atomicAdd(&deg[ei[2 * e + 1]], 1);
}

__global__ void k_scan(const int* __restrict__ deg, int* __restrict__ offs, int n) {
    __shared__ int s[1024];
    __shared__ int base_s;
    int t = threadIdx.x;
    if (t == 0) base_s = 0;
    __syncthreads();
    int nchunk = (n + 1023) / 1024;
    for (int ch = 0; ch < nchunk; ++ch) {
        int i = ch * 1024 + t;
        int v = (i < n) ? deg[i] : 0;
        s[t] = v;
        __syncthreads();
        for (int off = 1; off < 1024; off <<= 1) {
            int add = (t >= off) ? s[t - off] : 0;
            __syncthreads();
            s[t] += add;
            __syncthreads();
        }
        int incl = s[t];
        int base = base_s;
        if (i < n) offs[i] = base + incl - v;   // exclusive
        __syncthreads();
        if (t == 1023) base_s = base + s[1023];
        __syncthreads();
    }
    if (t == 0) offs[n] = base_s;
}

__global__ void k_copy_int(const int* __restrict__ a, int* __restrict__ b, int n) {
    int i = blockIdx.x * blockDim.x + threadIdx.x;
    if (i < n) b[i] = a[i];
}

__global__ void k_scatter(const int* __restrict__ ei, const int* __restrict__ ed,
                          int* __restrict__ cur, int* __restrict__ esort, int ne) {
    int e = blockIdx.x * blockDim.x + threadIdx.x;
    if (e < ne) {
        int dst = ei[2 * e + 1];
        int pos = atomicAdd(&cur[dst], 1);
        esort[pos] = (ed[e] << 16) | ei[2 * e];
    }
}

// bias precompute: bfb = b_f + b_b ; brz = (b_ih + b_hh)[0:2H]
__global__ void k_prep(const float* __restrict__ b_f, const float* __restrict__ b_b,
                       const float* __restrict__ b_ih, const float* __restrict__ b_hh,
                       float* __restrict__ bfb, float* __restrict__ brz) {
    int i = blockIdx.x * blockDim.x + threadIdx.x;
    if (i < HID) bfb[i] = b_f[i] + b_b[i];
    if (i < 2 * HID) brz[i] = b_ih[i] + b_hh[i];
}

// fp32 KxN -> fp16 NxK transpose (weights)
__global__ __launch_bounds__(256) void k_transpose(const float* __restrict__ in,
                                                   _Float16* __restrict__ out,
                                                   int K, int N) {
    __shared__ float tile[32][33];
    int n0 = blockIdx.x * 32, k0 = blockIdx.y * 32;
    int tx = threadIdx.x & 31, ty = threadIdx.x >> 5;   // 32 x 8
#pragma unroll
    for (int r = 0; r < 4; ++r) {
        int k = k0 + ty + r * 8;
        tile[ty + r * 8][tx] = in[(size_t)k * N + n0 + tx];
    }
    __syncthreads();
#pragma unroll
    for (int r = 0; r < 4; ++r) {
        int n = n0 + ty + r * 8;
        out[(size_t)n * K + k0 + tx] = (_Float16)tile[tx][ty + r * 8];
    }
}

__global__ void k_cvt(const float* __restrict__ in, _Float16* __restrict__ out, int n) {
    int i = blockIdx.x * blockDim.x + threadIdx.x;
    if (i < n) out[i] = (_Float16)in[i];
}

// ---------------------------------------------------------------------------
// Aggregation: one block (128 thr) per node, 8 fp16 channels each (16B loads).
// ---------------------------------------------------------------------------
__global__ __launch_bounds__(128) void k_agg(
    const _Float16* __restrict__ h, const int* __restrict__ offs,
    const int* __restrict__ esort,
    _Float16* __restrict__ aggF, _Float16* __restrict__ aggB,
    _Float16* __restrict__ aggU) {
    int node = blockIdx.x;
    int c = threadIdx.x * 8;
    float f[8], b[8], u[8];
#pragma unroll
    for (int j = 0; j < 8; ++j) { f[j] = 0.f; b[j] = 0.f; u[j] = 0.f; }
    int beg = offs[node], end = offs[node + 1];
    for (int e = beg; e < end; ++e) {
        int pk = esort[e];
        int src = pk & 0xFFFF;
        int dir = pk >> 16;
        half8 v = *(const half8*)(h + (size_t)src * HID + c);
        if (dir == 0) {
#pragma unroll
            for (int j = 0; j < 8; ++j) f[j] += (float)v[j];
        } else if (dir == 1) {
#pragma unroll
            for (int j = 0; j < 8; ++j) b[j] += (float)v[j];
        } else {
#pragma unroll
            for (int j = 0; j < 8; ++j) u[j] += (float)v[j];
        }
    }
    size_t o = (size_t)node * HID + c;
    half8 vf, vb, vu;
#pragma unroll
    for (int j = 0; j < 8; ++j) {
        vf[j] = (_Float16)f[j]; vb[j] = (_Float16)b[j]; vu[j] = (_Float16)u[j];
    }
    *(half8*)(aggF + o) = vf;
    *(half8*)(aggB + o) = vb;
    *(half8*)(aggU + o) = vu;
}

// ---------------------------------------------------------------------------
// fp16 MFMA GEMM, 128x256 tile, BK=32, 512 thr = 8 waves (2m x 4n), each wave
// a 64x64 microtile of 4x4 mfma_f32_16x16x32_f16. Output width fixed = HID.
// epi 0: v = acc+bias [+U]; write Cbf [, Cf]
// epi 2: GRU: nn=tanh(acc+bias+R*HG); o=relu((1-Z)*nn+Z*Hf); Hf=o, Cbf=o
// ---------------------------------------------------------------------------
#define BM 128
#define BN 256
#define BK 32
#define NTHR 512

__global__ __launch_bounds__(NTHR) void gemm_f16(
    const _Float16* __restrict__ A1, const _Float16* __restrict__ B1t,
    const _Float16* __restrict__ A2, const _Float16* __restrict__ B2t,
    const _Float16* __restrict__ U, const float* __restrict__ bias,
    const _Float16* __restrict__ R, const _Float16* __restrict__ Zg,
    const _Float16* __restrict__ HG, float* __restrict__ Hf,
    _Float16* __restrict__ Cbf, float* __restrict__ Cf,
    int M, int K, int epi) {
    __shared__ _Float16 As[BM * BK];   // 8 KB
    __shared__ _Float16 Bs[BN * BK];   // 16 KB
    int t = threadIdx.x;
    int bx, by;
    swizzle_xy(bx, by);
    int m0 = bx * BM, n0 = by * BN;
    int wid = t >> 6, lane = t & 63;
    int wm = wid & 1, wn = wid >> 1;            // 2 x 4 wave grid
    int quad = lane >> 4, mr = lane & 15;

    floatx4 acc[4][4] = {};

    int npair = (A2 != nullptr) ? 2 : 1;
    for (int p = 0; p < npair; ++p) {
        const _Float16* A = p ? A2 : A1;
        const _Float16* B = p ? B2t : B1t;
        for (int k0 = 0; k0 < K; k0 += BK) {
            {   // A tile 128x32: 1 gld16 per thread
                int row = t >> 2;
                int ce = (t & 3) * 8;
                gld16(A + (size_t)(m0 + row) * K + k0 + ce, As + t * 8);
            }
#pragma unroll
            for (int i = 0; i < 2; ++i) {       // B tile 256x32: 2 gld16
                int row = i * 128 + (t >> 2);
                int ce = (t & 3) * 8;
                gld16(B + (size_t)(n0 + row) * K + k0 + ce, Bs + i * 4096 + t * 8);
            }
            __syncthreads();
            half8 af[4], bfr[4];
#pragma unroll
            for (int i = 0; i < 4; ++i)
                af[i] = *(const half8*)(As + (wm * 64 + i * 16 + mr) * 32 + quad * 8);
#pragma unroll
            for (int j = 0; j < 4; ++j)
                bfr[j] = *(const half8*)(Bs + (wn * 64 + j * 16 + mr) * 32 + quad * 8);
#pragma unroll
            for (int i = 0; i < 4; ++i)
#pragma unroll
                for (int j = 0; j < 4; ++j)
                    acc[i][j] = __builtin_amdgcn_mfma_f32_16x16x32_f16(
                        af[i], bfr[j], acc[i][j], 0, 0, 0);
            __syncthreads();
        }
    }

#pragma unroll
    for (int i = 0; i < 4; ++i) {
#pragma unroll
        for (int j = 0; j < 4; ++j) {
            int n = n0 + wn * 64 + j * 16 + mr;
            float bv = bias[n];
#pragma unroll
            for (int r = 0; r < 4; ++r) {
                int m = m0 + wm * 64 + i * 16 + quad * 4 + r;
                if (m >= M) continue;
                size_t idx = (size_t)m * HID + n;
                float v = acc[i][j][r] + bv;
                if (epi == 0) {
                    if (U) v += (float)U[idx];
                    if (Cf) Cf[idx] = v;
                    Cbf[idx] = (_Float16)v;
                } else {
                    float rr = (float)R[idx], zz = (float)Zg[idx], hg = (float)HG[idx];
                    float hv = Hf[idx];
                    float nn = tanh_(v + rr * hg);
                    float o = fmaxf((1.f - zz) * nn + zz * hv, 0.f);
                    Hf[idx] = o;
                    Cbf[idx] = (_Float16)o;
                }
            }
        }
    }
}

// ---------------------------------------------------------------------------
// Fused gate GEMM over N=3072 of Wih^T / Whh^T (both 3072 x 1024, N x K):
//   ng0 in [0,2048):   C = sigmoid(msg@Wih[n] + h@Whh[n] + brz[n])  (r, z)
//   ng0 in [2048,3072): C = h@Whh[n] + b_hh[n]                      (hn-gate)
// Writes r->bufA, z->bufB, hn->bufC (each M x 1024).
// ---------------------------------------------------------------------------
__global__ __launch_bounds__(NTHR) void gemm_gates(
    const _Float16* __restrict__ msg, const _Float16* __restrict__ hbf,
    const _Float16* __restrict__ Wiht, const _Float16* __restrict__ Whht,
    const float* __restrict__ brz, const float* __restrict__ b_hh,
    _Float16* __restrict__ bufA, _Float16* __restrict__ bufB,
    _Float16* __restrict__ bufC, int M) {
    __shared__ _Float16 As[BM * BK];
    __shared__ _Float16 Bs[BN * BK];
    int t = threadIdx.x;
    int bx, by;
    swizzle_xy(bx, by);
    int m0 = bx * BM;
    int ng0 = by * BN;                  // global n in [0, 3072), 256-aligned
    int seg = ng0 >> 10;                // 0=r, 1=z, 2=hn
    int wid = t >> 6, lane = t & 63;
    int wm = wid & 1, wn = wid >> 1;
    int quad = lane >> 4, mr = lane & 15;

    const _Float16* A1 = (seg < 2) ? msg : hbf;
    const _Float16* B1 = ((seg < 2) ? Wiht : Whht) + (size_t)ng0 * HID;
    const _Float16* A2 = hbf;
    const _Float16* B2 = Whht + (size_t)ng0 * HID;
    int npair = (seg < 2) ? 2 : 1;

    floatx4 acc[4][4] = {};
    for (int p = 0; p < npair; ++p) {
        const _Float16* A = p ? A2 : A1;
        const _Float16* B = p ? B2 : B1;
        for (int k0 = 0; k0 < HID; k0 += BK) {
            {
                int row = t >> 2;
                int ce = (t & 3) * 8;
                gld16(A + (size_t)(m0 + row) * HID + k0 + ce, As + t * 8);
            }
#pragma unroll
            for (int i = 0; i < 2; ++i) {
                int row = i * 128 + (t >> 2);
                int ce = (t & 3) * 8;
                gld16(B + (size_t)row * HID + k0 + ce, Bs + i * 4096 + t * 8);
            }
            __syncthreads();
            half8 af[4], bfr[4];
#pragma unroll
            for (int i = 0; i < 4; ++i)
                af[i] = *(const half8*)(As + (wm * 64 + i * 16 + mr) * 32 + quad * 8);
#pragma unroll
            for (int j = 0; j < 4; ++j)
                bfr[j] = *(const half8*)(Bs + (wn * 64 + j * 16 + mr) * 32 + quad * 8);
#pragma unroll
            for (int i = 0; i < 4; ++i)
#pragma unroll
                for (int j = 0; j < 4; ++j)
                    acc[i][j] = __builtin_amdgcn_mfma_f32_16x16x32_f16(
                        af[i], bfr[j], acc[i][j], 0, 0, 0);
            __syncthreads();
        }
    }

    _Float16* Cb = (seg == 0) ? bufA : (seg == 1) ? bufB : bufC;
#pragma unroll
    for (int i = 0; i < 4; ++i) {
#pragma unroll
        for (int j = 0; j < 4; ++j) {
            int n = ng0 + wn * 64 + j * 16 + mr;       // global [0,3072)
            int nloc = n & 1023;
            float bv = (seg < 2) ? brz[n] : b_hh[n];
#pragma unroll
            for (int r = 0; r < 4; ++r) {
                int m = m0 + wm * 64 + i * 16 + quad * 4 + r;
                if (m >= M) continue;
                size_t idx = (size_t)m * HID + nloc;
                float v = acc[i][j][r] + bv;
                Cb[idx] = (_Float16)((seg < 2) ? sig_(v) : v);
            }
        }
    }
}

// ---------------------------------------------------------------------------
// Readout (fp32)
// ---------------------------------------------------------------------------
__global__ void k_colmax(const float* __restrict__ h, float* __restrict__ hmax) {
    int c = blockIdx.x * blockDim.x + threadIdx.x;
    int r0 = blockIdx.y * 200;
    int r1 = r0 + 200; if (r1 > N_NODES) r1 = N_NODES;
    float m = 0.f;                                      // h >= 0 post-relu
    for (int r = r0; r < r1; ++r)
        m = fmaxf(m, h[(size_t)r * HID + c]);
    atomicMax((int*)&hmax[c], __float_as_int(m));       // valid for floats >= 0
}

__global__ void k_r1(const float* __restrict__ hmax, const float* __restrict__ W,
                     const float* __restrict__ b, float* __restrict__ t1) {
    int j = blockIdx.x * blockDim.x + threadIdx.x;
    if (j >= HID) return;
    float acc = b[j];
    for (int k = 0; k < HID; ++k) acc += hmax[k] * W[(size_t)k * HID + j];
    t1[j] = fmaxf(acc, 0.f);
}

__global__ void k_r2(const float* __restrict__ t1, const float* __restrict__ W2,
                     const float* __restrict__ b2, float* __restrict__ out) {
    __shared__ float s[256];
    int t = threadIdx.x;
    float acc = 0.f;
    for (int i = t; i < HID; i += 256) acc += t1[i] * W2[i];
    s[t] = acc;
    __syncthreads();
    for (int st = 128; st > 0; st >>= 1) {
        if (t < st) s[t] += s[t + st];
        __syncthreads();
    }
    if (t == 0) out[0] = s[0] + b2[0];
}

// ---------------------------------------------------------------------------
extern "C" void kernel_launch(void* const* d_in, const int* in_sizes, int n_in,
                              void* d_out, int out_size, void* d_ws, size_t ws_size,
                              hipStream_t stream) {
    const float* node_features = (const float*)d_in[0];
    const int*   edge_index    = (const int*)d_in[1];
    const int*   edge_dirs     = (const int*)d_in[2];
    const float* W_in = (const float*)d_in[3];
    const float* b_in = (const float*)d_in[4];
    const float* W_f  = (const float*)d_in[5];
    const float* b_f  = (const float*)d_in[6];
    const float* W_b  = (const float*)d_in[7];
    const float* b_b  = (const float*)d_in[8];
    const float* W_ih = (const float*)d_in[9];
    const float* b_ih = (const float*)d_in[10];
    const float* W_hh = (const float*)d_in[11];
    const float* b_hh = (const float*)d_in[12];
    const float* W_r1 = (const float*)d_in[13];
    const float* b_r1 = (const float*)d_in[14];
    const float* W_r2 = (const float*)d_in[15];
    const float* b_r2 = (const float*)d_in[16];
    float* out = (float*)d_out;

    // ---- workspace layout ----
    float* ws = (float*)d_ws;
    size_t off = 0;
    auto allocf = [&](size_t n) { float* p = ws + off; off += n; return p; };
    const size_t PH = (size_t)M_PAD * HID;
    float* h_f32 = allocf(PH);          // fp32 GRU state
    float* bfb   = allocf(HID);
    float* brz   = allocf(2 * HID);
    float* hmax  = allocf(HID);
    float* t1    = allocf(HID);
    _Float16* hp = (_Float16*)(ws + off);
    size_t hoff = 0;
    auto alloch = [&](size_t n) { _Float16* p = hp + hoff; hoff += n; return p; };
    _Float16* h_bf  = alloch(PH);       // fp16 shadow of h
    _Float16* msg   = alloch(PH);
    _Float16* bufA  = alloch(PH);       // aggF -> r
    _Float16* bufB  = alloch(PH);       // aggB -> z
    _Float16* bufC  = alloch(PH);       // aggU -> hn-gate
    _Float16* X_bf  = alloch((size_t)M_PAD * IN_DIM);
    _Float16* Wint  = alloch((size_t)HID * IN_DIM);
    _Float16* Wft   = alloch((size_t)HID * HID);
    _Float16* Wbt   = alloch((size_t)HID * HID);
    _Float16* Wiht  = alloch((size_t)3 * HID * HID);   // 3072 x 1024 (N x K)
    _Float16* Whht  = alloch((size_t)3 * HID * HID);
    int* ibase = (int*)(hp + hoff);
    int* deg   = ibase;
    int* offs  = ibase + N_NODES;
    int* cur   = offs + N_NODES + 1;
    int* esort = cur + N_NODES;

    // ---- CSR build + prep ----
    hipMemsetAsync(deg, 0, N_NODES * sizeof(int), stream);
    hipMemsetAsync(hmax, 0, HID * sizeof(float), stream);
    k_hist<<<(N_EDGES + 255) / 256, 256, 0, stream>>>(edge_index, deg, N_EDGES);
    k_scan<<<1, 1024, 0, stream>>>(deg, offs, N_NODES);
    k_copy_int<<<(N_NODES + 255) / 256, 256, 0, stream>>>(offs, cur, N_NODES);
    k_scatter<<<(N_EDGES + 255) / 256, 256, 0, stream>>>(edge_index, edge_dirs, cur,
                                                         esort, N_EDGES);
    k_prep<<<8, 256, 0, stream>>>(b_f, b_b, b_ih, b_hh, bfb, brz);

    k_transpose<<<dim3(HID / 32, IN_DIM / 32), 256, 0, stream>>>(W_in, Wint, IN_DIM, HID);
    k_transpose<<<dim3(HID / 32, HID / 32), 256, 0, stream>>>(W_f, Wft, HID, HID);
    k_transpose<<<dim3(HID / 32, HID / 32), 256, 0, stream>>>(W_b, Wbt, HID, HID);
    k_transpose<<<dim3(3 * HID / 32, HID / 32), 256, 0, stream>>>(W_ih, Wiht, HID, 3 * HID);
    k_transpose<<<dim3(3 * HID / 32, HID / 32), 256, 0, stream>>>(W_hh, Whht, HID, 3 * HID);
    k_cvt<<<(N_NODES * IN_DIM + 255) / 256, 256, 0, stream>>>(node_features, X_bf,
                                                              N_NODES * IN_DIM);

    dim3 gg(M_PAD / BM, HID / BN);        // 79 x 4
    dim3 gg3(M_PAD / BM, 3 * HID / BN);   // 79 x 12

    // ---- input projection ----
    gemm_f16<<<gg, NTHR, 0, stream>>>(X_bf, Wint, nullptr, nullptr,
                                      nullptr, b_in, nullptr, nullptr, nullptr,
                                      nullptr, h_bf, h_f32, N_NODES, IN_DIM, 0);

    const size_t HH = (size_t)HID * HID;
    for (int layer = 0; layer < 8; ++layer) {
        k_agg<<<N_NODES, 128, 0, stream>>>(h_bf, offs, esort, bufA, bufB, bufC);
        // msg = aggF@W_f + aggB@W_b + aggU + (b_f+b_b)
        gemm_f16<<<gg, NTHR, 0, stream>>>(bufA, Wft, bufB, Wbt, bufC, bfb,
                                          nullptr, nullptr, nullptr, nullptr,
                                          msg, nullptr, N_NODES, HID, 0);
        // r,z,hn fused over N=3072 -> bufA, bufB, bufC
        gemm_gates<<<gg3, NTHR, 0, stream>>>(msg, h_bf, Wiht, Whht, brz, b_hh,
                                             bufA, bufB, bufC, N_NODES);
        // h = relu((1-z)*tanh(msg@Wih_n + b_ih_n + r*hn) + z*h)
        gemm_f16<<<gg, NTHR, 0, stream>>>(msg, Wiht + 2 * HH, nullptr, nullptr,
                                          nullptr, b_ih + 2 * HID,
                                          bufA, bufB, bufC, h_f32,
                                          h_bf, nullptr, N_NODES, HID, 2);
    }

    // ---- readout (fp32) ----
    {
        dim3 gm(HID / 256, 50);
        k_colmax<<<gm, 256, 0, stream>>>(h_f32, hmax);
    }
    k_r1<<<HID / 256, 256, 0, stream>>>(hmax, W_r1, b_r1, t1);
    k_r2<<<1, 256, 0, stream>>>(t1, W_r2, b_r2, out);
}